// Round 5
// baseline (1277.127 us; speedup 1.0000x reference)
//
#include <hip/hip_runtime.h>
#include <hip/hip_bf16.h>

#define BSZ 8
#define SEQ 8192
#define DIM 128
#define NCH 128   // chunks per sequence
#define CLEN 64   // tokens per chunk

typedef unsigned short u16;
typedef unsigned int u32;

__device__ __forceinline__ float lo2f(u32 w){ union{u32 i;float f;}u; u.i=w<<16; return u.f; }
__device__ __forceinline__ float hi2f(u32 w){ union{u32 i;float f;}u; u.i=w&0xffff0000u; return u.f; }
__device__ __forceinline__ float us2f(u16 w){ union{u32 i;float f;}u; u.i=((u32)w)<<16; return u.f; }
__device__ __forceinline__ u16 f2us(float f){
  __hip_bfloat16 h = __float2bfloat16(f);
  union{ __hip_bfloat16 b; u16 s; }u; u.b=h; return u.s;
}
__device__ __forceinline__ void unpack8(uint4 p, float* f){
  f[0]=lo2f(p.x); f[1]=hi2f(p.x); f[2]=lo2f(p.y); f[3]=hi2f(p.y);
  f[4]=lo2f(p.z); f[5]=hi2f(p.z); f[6]=lo2f(p.w); f[7]=hi2f(p.w);
}
__device__ __forceinline__ void unpack4(uint2 p, float* f){
  f[0]=lo2f(p.x); f[1]=hi2f(p.x); f[2]=lo2f(p.y); f[3]=hi2f(p.y);
}
__device__ __forceinline__ float wred64(float v){
  #pragma unroll
  for (int o=1;o<64;o<<=1) v += __shfl_xor(v,o,64);
  return v;
}
__device__ __forceinline__ float red16(float v){
  v += __shfl_xor(v,1,64); v += __shfl_xor(v,2,64);
  v += __shfl_xor(v,4,64); v += __shfl_xor(v,8,64);
  return v;
}
__device__ __forceinline__ float sigmoidf_(float z){ return 1.f/(1.f+__expf(-z)); }
__device__ __forceinline__ float gelu_tanh(float x){
  float y = 0.7978845608028654f * fmaf(0.044715f*x, x*x, x);
  float e = __expf(2.f*y);
  float th = 1.f - 2.f/(e+1.f);
  return 0.5f*x*(1.f+th);
}

// ---- dtype abstraction -------------------------------------------------------
// rnn_a in (0.9, 0.99). If data is bf16, even u16 indices 0,2,4,6 are elements
// 0..3 -> all in (0.85,1.0). If data is fp32, they are low mantissa halves ->
// random bits; P(all 4 in range) ~ 2e-14.
__device__ __forceinline__ bool data_is_f32(const void* avec){
  const u16* a=(const u16*)avec;
  bool bf = true;
  #pragma unroll
  for (int j=0;j<4;++j){ float v=us2f(a[2*j]); bf = bf && (v>0.85f) && (v<1.0f); }
  return !bf;
}
template<bool F32>
__device__ __forceinline__ float ldg(const void* p, size_t i){
  if (F32) return ((const float*)p)[i];
  return us2f(((const u16*)p)[i]);
}
template<bool F32>
__device__ __forceinline__ u16 ld16(const void* p, size_t i){   // load -> bf16 bits
  if (F32) return f2us(((const float*)p)[i]);
  return ((const u16*)p)[i];
}
template<bool F32>
__device__ __forceinline__ void stg(void* p, size_t i, float v){
  if (F32) ((float*)p)[i]=v; else ((u16*)p)[i]=f2us(v);
}

// ---------------------------------------------------------------- K0: affines
// aff[b*6+h], h: 0=cln1_s 1=cln1_b 2=gate1 3=cln2_s 4=cln2_b 5=gate2
template<bool F32>
__global__ __launch_bounds__(64) void k_aff(
    const void* __restrict__ c,
    const void* w0,const void* w1,const void* w2,const void* w3,const void* w4,const void* w5,
    const void* s0,const void* s1,const void* s2,const void* s3,const void* s4,const void* s5,
    const void* __restrict__ avec, float* __restrict__ aff)
{
  if (data_is_f32(avec)!=F32) return;
  const void* ws[6]={w0,w1,w2,w3,w4,w5};
  const void* bs[6]={s0,s1,s2,s3,s4,s5};
  int l = threadIdx.x;
  for (int b=0;b<BSZ;++b){
    #pragma unroll
    for (int h=0;h<6;++h){
      float v = ldg<F32>(c,b*128+l)*ldg<F32>(ws[h],l) + ldg<F32>(c,b*128+64+l)*ldg<F32>(ws[h],64+l);
      v = wred64(v);
      if (l==0) aff[b*6+h] = v + ldg<F32>(bs[h],0);
    }
  }
}

// -------- shared device routine: LN -> LN -> u -> gates -> a_t,b_t into t0,t1
template<bool F32>
__device__ __forceinline__ void compute_ab(
    const void* __restrict__ xg, const void* __restrict__ w_in, const void* __restrict__ b_in,
    const void* __restrict__ pos, const void* __restrict__ w_i, const void* __restrict__ b_i,
    const void* __restrict__ w_r, const void* __restrict__ b_r, const void* __restrict__ avec,
    const float* __restrict__ aff,
    u16* wbuf, float* t0, float* t1,
    int b, int ck, size_t base, int t)
{
  // stage w_in (as bf16 bits in LDS)
  for (int i=t;i<DIM*DIM;i+=256) wbuf[i]=ld16<F32>(w_in,i);

  // phase A: h=(1+s1)*ln(x)+b1 ; lnh=ln(h) -> t0
  {
    const float s1p = 1.f + aff[b*6+0];
    const float b1a = aff[b*6+1];
    const int wv = t>>6, ln = t&63;
    for (int i=0;i<16;++i){
      int r = wv*16 + i;
      float v0 = ldg<F32>(xg, base + (size_t)r*DIM + 2*ln);
      float v1 = ldg<F32>(xg, base + (size_t)r*DIM + 2*ln + 1);
      float m  = wred64(v0+v1)*(1.f/128.f);
      float d0=v0-m, d1=v1-m;
      float var = wred64(d0*d0+d1*d1)*(1.f/128.f);
      float rs = rsqrtf(var + 1e-6f);
      float h0 = fmaf(d0*rs, s1p, b1a);
      float h1 = fmaf(d1*rs, s1p, b1a);
      float m2 = wred64(h0+h1)*(1.f/128.f);
      float e0=h0-m2, e1=h1-m2;
      float var2 = wred64(e0*e0+e1*e1)*(1.f/128.f);
      float rs2 = rsqrtf(var2 + 1e-6f);
      ((float2*)(t0 + r*DIM))[ln] = make_float2(e0*rs2, e1*rs2);
    }
  }
  __syncthreads();

  const int cg = t & 15, rg = t >> 4;
  const int j0 = cg*8, r0 = rg*4;

  // phase B: u = lnh @ w_in + b_in + pos  -> t1
  {
    float acc[4][8];
    #pragma unroll
    for (int ii=0;ii<4;++ii){
      #pragma unroll
      for (int j=0;j<8;++j) acc[ii][j]=0.f;
    }
    #pragma unroll 4
    for (int k0=0;k0<128;++k0){
      int k = (k0 + rg*8) & 127;
      float wf[8]; unpack8(*(const uint4*)&wbuf[k*DIM + j0], wf);
      float h0=t0[(r0+0)*DIM+k], h1=t0[(r0+1)*DIM+k], h2=t0[(r0+2)*DIM+k], h3=t0[(r0+3)*DIM+k];
      #pragma unroll
      for (int j=0;j<8;++j){
        acc[0][j]=fmaf(h0,wf[j],acc[0][j]); acc[1][j]=fmaf(h1,wf[j],acc[1][j]);
        acc[2][j]=fmaf(h2,wf[j],acc[2][j]); acc[3][j]=fmaf(h3,wf[j],acc[3][j]);
      }
    }
    float bf[8];
    #pragma unroll
    for (int j=0;j<8;++j) bf[j]=ldg<F32>(b_in,j0+j);
    #pragma unroll
    for (int ii=0;ii<4;++ii){
      int r=r0+ii;
      #pragma unroll
      for (int j=0;j<8;++j)
        t1[r*DIM+j0+j] = acc[ii][j] + bf[j] + ldg<F32>(pos,(size_t)(ck*CLEN + r)*DIM + j0 + j);
    }
  }
  __syncthreads();

  // stage w_i
  for (int i=t;i<DIM*DIM;i+=256) wbuf[i]=ld16<F32>(w_i,i);
  __syncthreads();

  // phase C: gi = sigmoid(u @ w_i + b_i) -> regs
  float gia[4][8];
  {
    #pragma unroll
    for (int ii=0;ii<4;++ii){
      #pragma unroll
      for (int j=0;j<8;++j) gia[ii][j]=0.f;
    }
    #pragma unroll 4
    for (int k0=0;k0<128;++k0){
      int k = (k0 + rg*8) & 127;
      float wf[8]; unpack8(*(const uint4*)&wbuf[k*DIM + j0], wf);
      float u0=t1[(r0+0)*DIM+k], u1=t1[(r0+1)*DIM+k], u2=t1[(r0+2)*DIM+k], u3=t1[(r0+3)*DIM+k];
      #pragma unroll
      for (int j=0;j<8;++j){
        gia[0][j]=fmaf(u0,wf[j],gia[0][j]); gia[1][j]=fmaf(u1,wf[j],gia[1][j]);
        gia[2][j]=fmaf(u2,wf[j],gia[2][j]); gia[3][j]=fmaf(u3,wf[j],gia[3][j]);
      }
    }
    #pragma unroll
    for (int ii=0;ii<4;++ii){
      #pragma unroll
      for (int j=0;j<8;++j) gia[ii][j] = sigmoidf_(gia[ii][j]+ldg<F32>(b_i,j0+j));
    }
  }
  __syncthreads();

  // stage w_r
  for (int i=t;i<DIM*DIM;i+=256) wbuf[i]=ld16<F32>(w_r,i);
  __syncthreads();

  // phase D: gr accumulate -> regs
  float gra[4][8];
  {
    #pragma unroll
    for (int ii=0;ii<4;++ii){
      #pragma unroll
      for (int j=0;j<8;++j) gra[ii][j]=0.f;
    }
    #pragma unroll 4
    for (int k0=0;k0<128;++k0){
      int k = (k0 + rg*8) & 127;
      float wf[8]; unpack8(*(const uint4*)&wbuf[k*DIM + j0], wf);
      float u0=t1[(r0+0)*DIM+k], u1=t1[(r0+1)*DIM+k], u2=t1[(r0+2)*DIM+k], u3=t1[(r0+3)*DIM+k];
      #pragma unroll
      for (int j=0;j<8;++j){
        gra[0][j]=fmaf(u0,wf[j],gra[0][j]); gra[1][j]=fmaf(u1,wf[j],gra[1][j]);
        gra[2][j]=fmaf(u2,wf[j],gra[2][j]); gra[3][j]=fmaf(u3,wf[j],gra[3][j]);
      }
    }
  }
  __syncthreads();   // everyone done reading u (t1) before a_t/b_t overwrite t0/t1

  // a_t -> t0, b_t -> t1
  {
    float la[8];
    #pragma unroll
    for (int j=0;j<8;++j) la[j]=__logf(ldg<F32>(avec,j0+j));
    float brf[8];
    #pragma unroll
    for (int j=0;j<8;++j) brf[j]=ldg<F32>(b_r,j0+j);
    #pragma unroll
    for (int ii=0;ii<4;++ii){
      int r=r0+ii;
      #pragma unroll
      for (int j=0;j<8;++j){
        float g = sigmoidf_(gra[ii][j]+brf[j]);
        float a = __expf(8.f*g*la[j]);
        float u = t1[r*DIM+j0+j];
        t0[r*DIM+j0+j]=a;
        t1[r*DIM+j0+j]=sqrtf(fmaxf(1.f-a*a,0.f))*gia[ii][j]*u;
      }
    }
  }
  __syncthreads();
}

// -------------------- K1: compute a,b -> chunk summaries only (96 KB LDS)
template<bool F32>
__global__ __launch_bounds__(256,1) void k_pre(
    const void* __restrict__ xg, const void* __restrict__ w_in, const void* __restrict__ b_in,
    const void* __restrict__ pos, const void* __restrict__ w_i, const void* __restrict__ b_i,
    const void* __restrict__ w_r, const void* __restrict__ b_r, const void* __restrict__ avec,
    const float* __restrict__ aff,
    float* __restrict__ Ag, float* __restrict__ Bfg, float* __restrict__ Bbg)
{
  if (data_is_f32(avec)!=F32) return;
  __shared__ u16   wbuf[DIM*DIM];     // 32 KB
  __shared__ float t0[CLEN*DIM];      // 32 KB -> a_t
  __shared__ float t1[CLEN*DIM];      // 32 KB -> b_t
  const int t  = threadIdx.x;
  const int b  = blockIdx.x >> 7;
  const int ck = blockIdx.x & (NCH-1);
  const size_t base = ((size_t)(b*SEQ + ck*CLEN))*DIM;

  compute_ab<F32>(xg,w_in,b_in,pos,w_i,b_i,w_r,b_r,avec,aff,wbuf,t0,t1,b,ck,base,t);

  // chunk-local scans -> summaries
  const int sbase = (b*NCH+ck)*DIM;
  if (t < 128){
    float h=0.f, p=1.f;
    #pragma unroll 4
    for (int tt=0;tt<CLEN;++tt){ float a=t0[tt*DIM+t], bb=t1[tt*DIM+t]; h=fmaf(a,h,bb); p*=a; }
    Ag[sbase+t]=p; Bfg[sbase+t]=h;
  } else {
    int ch=t-128; float h=0.f;
    #pragma unroll 4
    for (int tt=CLEN-1;tt>=0;--tt){ h=fmaf(t0[tt*DIM+ch],h,t1[tt*DIM+ch]); }
    Bbg[sbase+ch]=h;
  }
}

// ------------------------------------------------ K2: prefix over chunk summaries
__global__ __launch_bounds__(128) void k_chunkscan(
    const float* __restrict__ Ag, const float* __restrict__ Bfg, const float* __restrict__ Bbg,
    float* __restrict__ Hf, float* __restrict__ Hb)
{
  const int dir = blockIdx.x >> 3, b = blockIdx.x & 7, ch = threadIdx.x;
  float s = 0.f;
  if (dir==0){
    for (int c=0;c<NCH;++c){ size_t i=((size_t)(b*NCH+c))*DIM+ch; Hf[i]=s; s=fmaf(Ag[i],s,Bfg[i]); }
  } else {
    for (int c=NCH-1;c>=0;--c){ size_t i=((size_t)(b*NCH+c))*DIM+ch; Hb[i]=s; s=fmaf(Ag[i],s,Bbg[i]); }
  }
}

// -------------------- K3: recompute a,b + seeded scan + out proj + residual (96 KB LDS)
template<bool F32>
__global__ __launch_bounds__(256,1) void k_scan(
    const void* __restrict__ xg, const void* __restrict__ w_in, const void* __restrict__ b_in,
    const void* __restrict__ pos, const void* __restrict__ w_i, const void* __restrict__ b_i,
    const void* __restrict__ w_r, const void* __restrict__ b_r, const void* __restrict__ avec,
    const float* __restrict__ aff,
    const float* __restrict__ Hf, const float* __restrict__ Hb,
    const void* __restrict__ w_out, const void* __restrict__ b_out,
    void* __restrict__ outg)
{
  if (data_is_f32(avec)!=F32) return;
  __shared__ u16   wbuf[DIM*DIM];     // 32 KB: weights, then hcat [64][256] bf16
  __shared__ float t0[CLEN*DIM];      // 32 KB: a_t, then w_out halves (as u16)
  __shared__ float t1[CLEN*DIM];      // 32 KB: b_t
  const int t  = threadIdx.x;
  const int b  = blockIdx.x >> 7;
  const int ck = blockIdx.x & (NCH-1);
  const size_t base = ((size_t)(b*SEQ + ck*CLEN))*DIM;

  compute_ab<F32>(xg,w_in,b_in,pos,w_i,b_i,w_r,b_r,avec,aff,wbuf,t0,t1,b,ck,base,t);

  // seeded scans -> hcat (values consumed into regs before hcat overwrites wbuf? no:
  // t0/t1 hold a,b; hcat = wbuf which held w_r, free now)
  u16* hcat = wbuf;   // [64][256]
  const int pbase=(b*NCH+ck)*DIM;
  if (t<128){
    float h=Hf[pbase+t];
    #pragma unroll 4
    for (int tt=0;tt<CLEN;++tt){
      h=fmaf(t0[tt*DIM+t],h,t1[tt*DIM+t]);
      hcat[tt*256+t]=f2us(h);
    }
  } else {
    int ch=t-128;
    float h=Hb[pbase+ch];
    #pragma unroll 4
    for (int tt=CLEN-1;tt>=0;--tt){
      h=fmaf(t0[tt*DIM+ch],h,t1[tt*DIM+ch]);
      hcat[tt*256+128+ch]=f2us(h);
    }
  }
  __syncthreads();

  const int cg=t&15, rg=t>>4, j0=cg*8, r0=rg*4;
  u16* wl=(u16*)t0;   // 128x128 u16 = 32 KB (t0/t1 free now)
  float acc[4][8];
  #pragma unroll
  for (int ii=0;ii<4;++ii){
    #pragma unroll
    for (int j=0;j<8;++j) acc[ii][j]=0.f;
  }
  for (int half=0; half<2; ++half){
    for (int i=t;i<DIM*DIM;i+=256) wl[i]=ld16<F32>(w_out, half*DIM*DIM + i);
    __syncthreads();
    #pragma unroll 2
    for (int k0=0;k0<128;++k0){
      int k=(k0+rg*8)&127;
      float wf[8]; unpack8(*(const uint4*)&wl[k*DIM+j0], wf);
      int hb_ = half*128 + k;
      float h0=us2f(hcat[(r0+0)*256+hb_]); float h1=us2f(hcat[(r0+1)*256+hb_]);
      float h2=us2f(hcat[(r0+2)*256+hb_]); float h3=us2f(hcat[(r0+3)*256+hb_]);
      #pragma unroll
      for (int j=0;j<8;++j){
        acc[0][j]=fmaf(h0,wf[j],acc[0][j]); acc[1][j]=fmaf(h1,wf[j],acc[1][j]);
        acc[2][j]=fmaf(h2,wf[j],acc[2][j]); acc[3][j]=fmaf(h3,wf[j],acc[3][j]);
      }
    }
    __syncthreads();
  }
  const float g1=aff[b*6+2];
  float bo[8];
  #pragma unroll
  for (int j=0;j<8;++j) bo[j]=ldg<F32>(b_out,j0+j);
  #pragma unroll
  for (int ii=0;ii<4;++ii){
    int r=r0+ii;
    #pragma unroll
    for (int j=0;j<8;++j){
      float xv = ldg<F32>(xg, base+(size_t)r*DIM+j0+j);
      float o = fmaf(g1, acc[ii][j]+bo[j], xv);
      stg<F32>(outg, base+(size_t)r*DIM+j0+j, o);
    }
  }
}

// -------------------- K4: cLN2 + gelu MLP + gated residual (96 KB LDS)
template<bool F32>
__global__ __launch_bounds__(256,1) void k_mlp(
    const void* __restrict__ w1, const void* __restrict__ b1v,
    const void* __restrict__ w2, const void* __restrict__ b2v,
    const void* __restrict__ avec,
    const float* __restrict__ aff, void* __restrict__ outg)
{
  if (data_is_f32(avec)!=F32) return;
  __shared__ u16 h2l[CLEN*DIM];   // 16 KB
  __shared__ u16 m1l[CLEN*512];   // 64 KB
  __shared__ u16 wst[128*64];     // 16 KB
  const int t=threadIdx.x;
  const int b=blockIdx.x>>7;
  const size_t base=(size_t)blockIdx.x*CLEN*DIM;
  const int cg=t&15, rg=t>>4, j0=cg*8, r0=rg*4;
  const float s2p=1.f+aff[b*6+3], b2a=aff[b*6+4], g2=aff[b*6+5];

  // step 0: h2 = (1+s2)*LN(x1)+b2  (x1 = outg)
  #pragma unroll
  for (int ii=0;ii<4;++ii){
    int r=r0+ii;
    float o[8];
    #pragma unroll
    for (int j=0;j<8;++j) o[j]=ldg<F32>(outg, base+(size_t)r*DIM+j0+j);
    float s=0.f;
    #pragma unroll
    for (int j=0;j<8;++j) s+=o[j];
    s=red16(s); float m=s*(1.f/128.f);
    float q2=0.f;
    #pragma unroll
    for (int j=0;j<8;++j){ float d=o[j]-m; q2+=d*d; }
    q2=red16(q2); float rs=rsqrtf(q2*(1.f/128.f)+1e-6f);
    #pragma unroll
    for (int j=0;j<8;++j) h2l[r*DIM+j0+j] = f2us(fmaf((o[j]-m)*rs, s2p, b2a));
  }
  __syncthreads();

  const int c0 = cg*4;  // column within a 64-col w1 panel
  // first matmul + gelu: 8 panels of 64 cols
  for (int jb=0;jb<8;++jb){
    for (int i=t;i<128*64;i+=256) wst[i] = ld16<F32>(w1, (size_t)(i>>6)*512 + jb*64 + (i&63));
    __syncthreads();
    float acc[4][4];
    #pragma unroll
    for (int ii=0;ii<4;++ii){
      #pragma unroll
      for (int j=0;j<4;++j) acc[ii][j]=0.f;
    }
    #pragma unroll 4
    for (int k0=0;k0<128;++k0){
      int k=(k0+rg*8)&127;
      float wf[4]; unpack4(*(const uint2*)&wst[k*64+c0], wf);
      float h0=us2f(h2l[(r0+0)*DIM+k]); float h1=us2f(h2l[(r0+1)*DIM+k]);
      float h2=us2f(h2l[(r0+2)*DIM+k]); float h3=us2f(h2l[(r0+3)*DIM+k]);
      #pragma unroll
      for (int j=0;j<4;++j){
        acc[0][j]=fmaf(h0,wf[j],acc[0][j]); acc[1][j]=fmaf(h1,wf[j],acc[1][j]);
        acc[2][j]=fmaf(h2,wf[j],acc[2][j]); acc[3][j]=fmaf(h3,wf[j],acc[3][j]);
      }
    }
    float bf[4];
    #pragma unroll
    for (int j=0;j<4;++j) bf[j]=ldg<F32>(b1v, jb*64+c0+j);
    #pragma unroll
    for (int ii=0;ii<4;++ii){
      u32 p0=(u32)f2us(gelu_tanh(acc[ii][0]+bf[0])) | ((u32)f2us(gelu_tanh(acc[ii][1]+bf[1]))<<16);
      u32 p1=(u32)f2us(gelu_tanh(acc[ii][2]+bf[2])) | ((u32)f2us(gelu_tanh(acc[ii][3]+bf[3]))<<16);
      *(u32*)&m1l[(r0+ii)*512 + jb*64 + c0]     = p0;
      *(u32*)&m1l[(r0+ii)*512 + jb*64 + c0 + 2] = p1;
    }
    __syncthreads();
  }

  // second matmul: 8 chunks of 64 rows of w2
  float acc2[4][8];
  #pragma unroll
  for (int ii=0;ii<4;++ii){
    #pragma unroll
    for (int j=0;j<8;++j) acc2[ii][j]=0.f;
  }
  for (int kb=0;kb<8;++kb){
    for (int i=t;i<64*128;i+=256) wst[i] = ld16<F32>(w2, (size_t)(kb*64+(i>>7))*128 + (i&127));
    __syncthreads();
    #pragma unroll 4
    for (int kk0=0;kk0<64;++kk0){
      int kk=(kk0+rg*4)&63;
      float wf[8]; unpack8(*(const uint4*)&wst[kk*DIM+j0], wf);
      float m0=us2f(m1l[(r0+0)*512 + kb*64 + kk]); float m1=us2f(m1l[(r0+1)*512 + kb*64 + kk]);
      float m2=us2f(m1l[(r0+2)*512 + kb*64 + kk]); float m3=us2f(m1l[(r0+3)*512 + kb*64 + kk]);
      #pragma unroll
      for (int j=0;j<8;++j){
        acc2[0][j]=fmaf(m0,wf[j],acc2[0][j]); acc2[1][j]=fmaf(m1,wf[j],acc2[1][j]);
        acc2[2][j]=fmaf(m2,wf[j],acc2[2][j]); acc2[3][j]=fmaf(m3,wf[j],acc2[3][j]);
      }
    }
    __syncthreads();
  }
  float bf2[8];
  #pragma unroll
  for (int j=0;j<8;++j) bf2[j]=ldg<F32>(b2v,j0+j);
  #pragma unroll
  for (int ii=0;ii<4;++ii){
    int r=r0+ii;
    #pragma unroll
    for (int j=0;j<8;++j){
      float xv = ldg<F32>(outg, base+(size_t)r*DIM+j0+j);
      stg<F32>(outg, base+(size_t)r*DIM+j0+j, fmaf(g2, acc2[ii][j]+bf2[j], xv));
    }
  }
}

// ----------------------------------------------------------------------------
extern "C" void kernel_launch(void* const* d_in, const int* in_sizes, int n_in,
                              void* d_out, int out_size, void* d_ws, size_t ws_size,
                              hipStream_t stream)
{
  (void)in_sizes; (void)n_in; (void)out_size; (void)ws_size;
  const void* x   =d_in[0];
  const void* c   =d_in[1];
  const void* c1sw=d_in[2];  const void* c1sb=d_in[3];
  const void* c1bw=d_in[4];  const void* c1bb=d_in[5];
  const void* g1w =d_in[6];  const void* g1b =d_in[7];
  const void* win =d_in[8];  const void* binv=d_in[9];
  const void* pos =d_in[10];
  const void* wi  =d_in[11]; const void* biv =d_in[12];
  const void* wr  =d_in[13]; const void* brv =d_in[14];
  const void* av  =d_in[15];
  const void* wout=d_in[16]; const void* bout=d_in[17];
  const void* w1  =d_in[24]; const void* b1v =d_in[25];
  const void* w2  =d_in[26]; const void* b2v =d_in[27];
  const void* c2sw=d_in[18]; const void* c2sb=d_in[19];
  const void* c2bw=d_in[20]; const void* c2bb=d_in[21];
  const void* g2w =d_in[22]; const void* g2b =d_in[23];

  // workspace: 5*131072 + 64 floats = 2.62 MB total
  float* wsf  = (float*)d_ws;
  float* Ag   = wsf;
  float* Bfg  = Ag   + 131072;
  float* Bbg  = Bfg  + 131072;
  float* Hf   = Bbg  + 131072;
  float* Hb   = Hf   + 131072;
  float* aff  = Hb   + 131072;       // 48 (pad 64)

  void* outg = d_out;

  // Launch both dtype variants of every kernel; the detector in each kernel
  // makes exactly one variant do the work (identical sequence every call).
  k_aff<false><<<dim3(1),dim3(64),0,stream>>>(c, c1sw,c1bw,g1w,c2sw,c2bw,g2w,
                                              c1sb,c1bb,g1b,c2sb,c2bb,g2b, av, aff);
  k_aff<true ><<<dim3(1),dim3(64),0,stream>>>(c, c1sw,c1bw,g1w,c2sw,c2bw,g2w,
                                              c1sb,c1bb,g1b,c2sb,c2bb,g2b, av, aff);
  k_pre<false><<<dim3(BSZ*NCH),dim3(256),0,stream>>>(x,win,binv,pos,wi,biv,wr,brv,av,aff,
                                                     Ag,Bfg,Bbg);
  k_pre<true ><<<dim3(BSZ*NCH),dim3(256),0,stream>>>(x,win,binv,pos,wi,biv,wr,brv,av,aff,
                                                     Ag,Bfg,Bbg);
  k_chunkscan<<<dim3(16),dim3(128),0,stream>>>(Ag,Bfg,Bbg,Hf,Hb);
  k_scan<false><<<dim3(BSZ*NCH),dim3(256),0,stream>>>(x,win,binv,pos,wi,biv,wr,brv,av,aff,
                                                      Hf,Hb,wout,bout,outg);
  k_scan<true ><<<dim3(BSZ*NCH),dim3(256),0,stream>>>(x,win,binv,pos,wi,biv,wr,brv,av,aff,
                                                      Hf,Hb,wout,bout,outg);
  k_mlp<false><<<dim3(BSZ*NCH),dim3(256),0,stream>>>(w1,b1v,w2,b2v,av,aff,outg);
  k_mlp<true ><<<dim3(BSZ*NCH),dim3(256),0,stream>>>(w1,b1v,w2,b2v,av,aff,outg);
}

// Round 6
// 728.172 us; speedup vs baseline: 1.7539x; 1.7539x over previous
//
#include <hip/hip_runtime.h>
#include <hip/hip_bf16.h>

#define BSZ 8
#define SEQ 8192
#define DIM 128
#define NCH 128   // chunks per sequence
#define CLEN 64   // tokens per chunk

typedef unsigned short u16;
typedef unsigned int u32;
typedef short bf16x8 __attribute__((ext_vector_type(8)));
typedef float f32x4  __attribute__((ext_vector_type(4)));

__device__ __forceinline__ float us2f(u16 w){ union{u32 i;float f;}u; u.i=((u32)w)<<16; return u.f; }
__device__ __forceinline__ u16 f2us(float f){
  __hip_bfloat16 h = __float2bfloat16(f);
  union{ __hip_bfloat16 b; u16 s; }u; u.b=h; return u.s;
}
__device__ __forceinline__ float wred64(float v){
  #pragma unroll
  for (int o=1;o<64;o<<=1) v += __shfl_xor(v,o,64);
  return v;
}
__device__ __forceinline__ float red16(float v){
  v += __shfl_xor(v,1,64); v += __shfl_xor(v,2,64);
  v += __shfl_xor(v,4,64); v += __shfl_xor(v,8,64);
  return v;
}
__device__ __forceinline__ float sigmoidf_(float z){ return 1.f/(1.f+__expf(-z)); }
__device__ __forceinline__ float gelu_tanh(float x){
  float y = 0.7978845608028654f * fmaf(0.044715f*x, x*x, x);
  float e = __expf(2.f*y);
  float th = 1.f - 2.f/(e+1.f);
  return 0.5f*x*(1.f+th);
}

// ---------------------------------------------------------------- K0: affines
// aff[b*6+h], h: 0=cln1_s 1=cln1_b 2=gate1 3=cln2_s 4=cln2_b 5=gate2
__global__ __launch_bounds__(64) void k_aff(
    const float* __restrict__ c,
    const float* w0,const float* w1,const float* w2,const float* w3,const float* w4,const float* w5,
    const float* s0,const float* s1,const float* s2,const float* s3,const float* s4,const float* s5,
    float* __restrict__ aff)
{
  const float* ws[6]={w0,w1,w2,w3,w4,w5};
  const float* bs[6]={s0,s1,s2,s3,s4,s5};
  int l = threadIdx.x;
  for (int b=0;b<BSZ;++b){
    #pragma unroll
    for (int h=0;h<6;++h){
      float v = c[b*128+l]*ws[h][l] + c[b*128+64+l]*ws[h][64+l];
      v = wred64(v);
      if (l==0) aff[b*6+h] = v + bs[h][0];
    }
  }
}

// ------------------------------------------- K0b: weight transpose fp32->bf16
// w1t[512][128], w2t[128][512], wot[128][256]  (row-major [N][K])
__global__ __launch_bounds__(256) void k_prep(
    const float* __restrict__ w1, const float* __restrict__ w2, const float* __restrict__ wo,
    u16* __restrict__ w1t, u16* __restrict__ w2t, u16* __restrict__ wot)
{
  int i = blockIdx.x*256 + threadIdx.x;          // 65536 threads
  { int n=i>>7, k=i&127; w1t[i] = f2us(w1[k*512+n]); }
  { int n=i>>9, k=i&511; w2t[i] = f2us(w2[k*128+n]); }
  if (i < 32768){ int n=i>>8, k=i&255; wot[i] = f2us(wo[k*128+n]); }
}

// -------- shared device routine: LN -> LN -> u -> gates -> a_t,b_t into t0,t1
__device__ __forceinline__ void compute_ab(
    const float* __restrict__ xg, const float* __restrict__ w_in, const float* __restrict__ b_in,
    const float* __restrict__ pos, const float* __restrict__ w_i, const float* __restrict__ b_i,
    const float* __restrict__ w_r, const float* __restrict__ b_r, const float* __restrict__ avec,
    const float* __restrict__ aff,
    u16* wbuf, float* t0, float* t1,
    int b, int ck, size_t base, int t)
{
  // stage w_in as bf16
  for (int i=t;i<DIM*DIM;i+=256) wbuf[i]=f2us(w_in[i]);

  // phase A: h=(1+s1)*ln(x)+b1 ; lnh=ln(h) -> t0
  {
    const float s1p = 1.f + aff[b*6+0];
    const float b1a = aff[b*6+1];
    const int wv = t>>6, ln = t&63;
    for (int i=0;i<16;++i){
      int r = wv*16 + i;
      float2 v = *(const float2*)(xg + base + (size_t)r*DIM + 2*ln);
      float v0=v.x, v1=v.y;
      float m  = wred64(v0+v1)*(1.f/128.f);
      float d0=v0-m, d1=v1-m;
      float var = wred64(d0*d0+d1*d1)*(1.f/128.f);
      float rs = rsqrtf(var + 1e-6f);
      float h0 = fmaf(d0*rs, s1p, b1a);
      float h1 = fmaf(d1*rs, s1p, b1a);
      float m2 = wred64(h0+h1)*(1.f/128.f);
      float e0=h0-m2, e1=h1-m2;
      float var2 = wred64(e0*e0+e1*e1)*(1.f/128.f);
      float rs2 = rsqrtf(var2 + 1e-6f);
      ((float2*)(t0 + r*DIM))[ln] = make_float2(e0*rs2, e1*rs2);
    }
  }
  __syncthreads();

  const int cg = t & 15, rg = t >> 4;
  const int j0 = cg*8, r0 = rg*4;

  // phase B: u = lnh @ w_in + b_in + pos  -> t1
  {
    float acc[4][8];
    #pragma unroll
    for (int ii=0;ii<4;++ii){
      #pragma unroll
      for (int j=0;j<8;++j) acc[ii][j]=0.f;
    }
    #pragma unroll 4
    for (int k0=0;k0<128;++k0){
      int k = (k0 + rg*8) & 127;
      float wf[8];
      { uint4 p = *(const uint4*)&wbuf[k*DIM + j0];
        wf[0]=us2f((u16)p.x); wf[1]=us2f((u16)(p.x>>16));
        wf[2]=us2f((u16)p.y); wf[3]=us2f((u16)(p.y>>16));
        wf[4]=us2f((u16)p.z); wf[5]=us2f((u16)(p.z>>16));
        wf[6]=us2f((u16)p.w); wf[7]=us2f((u16)(p.w>>16)); }
      float h0=t0[(r0+0)*DIM+k], h1=t0[(r0+1)*DIM+k], h2=t0[(r0+2)*DIM+k], h3=t0[(r0+3)*DIM+k];
      #pragma unroll
      for (int j=0;j<8;++j){
        acc[0][j]=fmaf(h0,wf[j],acc[0][j]); acc[1][j]=fmaf(h1,wf[j],acc[1][j]);
        acc[2][j]=fmaf(h2,wf[j],acc[2][j]); acc[3][j]=fmaf(h3,wf[j],acc[3][j]);
      }
    }
    #pragma unroll
    for (int ii=0;ii<4;++ii){
      int r=r0+ii;
      #pragma unroll
      for (int j=0;j<8;++j)
        t1[r*DIM+j0+j] = acc[ii][j] + b_in[j0+j] + pos[(size_t)(ck*CLEN + r)*DIM + j0 + j];
    }
  }
  __syncthreads();

  for (int i=t;i<DIM*DIM;i+=256) wbuf[i]=f2us(w_i[i]);
  __syncthreads();

  // phase C: gi
  float gia[4][8];
  {
    #pragma unroll
    for (int ii=0;ii<4;++ii){
      #pragma unroll
      for (int j=0;j<8;++j) gia[ii][j]=0.f;
    }
    #pragma unroll 4
    for (int k0=0;k0<128;++k0){
      int k = (k0 + rg*8) & 127;
      float wf[8];
      { uint4 p = *(const uint4*)&wbuf[k*DIM + j0];
        wf[0]=us2f((u16)p.x); wf[1]=us2f((u16)(p.x>>16));
        wf[2]=us2f((u16)p.y); wf[3]=us2f((u16)(p.y>>16));
        wf[4]=us2f((u16)p.z); wf[5]=us2f((u16)(p.z>>16));
        wf[6]=us2f((u16)p.w); wf[7]=us2f((u16)(p.w>>16)); }
      float u0=t1[(r0+0)*DIM+k], u1=t1[(r0+1)*DIM+k], u2=t1[(r0+2)*DIM+k], u3=t1[(r0+3)*DIM+k];
      #pragma unroll
      for (int j=0;j<8;++j){
        gia[0][j]=fmaf(u0,wf[j],gia[0][j]); gia[1][j]=fmaf(u1,wf[j],gia[1][j]);
        gia[2][j]=fmaf(u2,wf[j],gia[2][j]); gia[3][j]=fmaf(u3,wf[j],gia[3][j]);
      }
    }
    #pragma unroll
    for (int ii=0;ii<4;++ii){
      #pragma unroll
      for (int j=0;j<8;++j) gia[ii][j] = sigmoidf_(gia[ii][j]+b_i[j0+j]);
    }
  }
  __syncthreads();

  for (int i=t;i<DIM*DIM;i+=256) wbuf[i]=f2us(w_r[i]);
  __syncthreads();

  // phase D: gr
  float gra[4][8];
  {
    #pragma unroll
    for (int ii=0;ii<4;++ii){
      #pragma unroll
      for (int j=0;j<8;++j) gra[ii][j]=0.f;
    }
    #pragma unroll 4
    for (int k0=0;k0<128;++k0){
      int k = (k0 + rg*8) & 127;
      float wf[8];
      { uint4 p = *(const uint4*)&wbuf[k*DIM + j0];
        wf[0]=us2f((u16)p.x); wf[1]=us2f((u16)(p.x>>16));
        wf[2]=us2f((u16)p.y); wf[3]=us2f((u16)(p.y>>16));
        wf[4]=us2f((u16)p.z); wf[5]=us2f((u16)(p.z>>16));
        wf[6]=us2f((u16)p.w); wf[7]=us2f((u16)(p.w>>16)); }
      float u0=t1[(r0+0)*DIM+k], u1=t1[(r0+1)*DIM+k], u2=t1[(r0+2)*DIM+k], u3=t1[(r0+3)*DIM+k];
      #pragma unroll
      for (int j=0;j<8;++j){
        gra[0][j]=fmaf(u0,wf[j],gra[0][j]); gra[1][j]=fmaf(u1,wf[j],gra[1][j]);
        gra[2][j]=fmaf(u2,wf[j],gra[2][j]); gra[3][j]=fmaf(u3,wf[j],gra[3][j]);
      }
    }
  }
  __syncthreads();

  // a_t -> t0, b_t -> t1
  {
    float la[8], brf[8];
    #pragma unroll
    for (int j=0;j<8;++j){ la[j]=__logf(avec[j0+j]); brf[j]=b_r[j0+j]; }
    #pragma unroll
    for (int ii=0;ii<4;++ii){
      int r=r0+ii;
      #pragma unroll
      for (int j=0;j<8;++j){
        float g = sigmoidf_(gra[ii][j]+brf[j]);
        float a = __expf(8.f*g*la[j]);
        float u = t1[r*DIM+j0+j];
        t0[r*DIM+j0+j]=a;
        t1[r*DIM+j0+j]=sqrtf(fmaxf(1.f-a*a,0.f))*gia[ii][j]*u;
      }
    }
  }
  __syncthreads();
}

// -------------------- K1: compute a,b -> chunk summaries
__global__ __launch_bounds__(256,1) void k_pre(
    const float* __restrict__ xg, const float* __restrict__ w_in, const float* __restrict__ b_in,
    const float* __restrict__ pos, const float* __restrict__ w_i, const float* __restrict__ b_i,
    const float* __restrict__ w_r, const float* __restrict__ b_r, const float* __restrict__ avec,
    const float* __restrict__ aff,
    float* __restrict__ Ag, float* __restrict__ Bfg, float* __restrict__ Bbg)
{
  __shared__ u16   wbuf[DIM*DIM];
  __shared__ float t0[CLEN*DIM];
  __shared__ float t1[CLEN*DIM];
  const int t  = threadIdx.x;
  const int b  = blockIdx.x >> 7;
  const int ck = blockIdx.x & (NCH-1);
  const size_t base = ((size_t)(b*SEQ + ck*CLEN))*DIM;

  compute_ab(xg,w_in,b_in,pos,w_i,b_i,w_r,b_r,avec,aff,wbuf,t0,t1,b,ck,base,t);

  const int sbase = (b*NCH+ck)*DIM;
  if (t < 128){
    float h=0.f, p=1.f;
    #pragma unroll 4
    for (int tt=0;tt<CLEN;++tt){ float a=t0[tt*DIM+t], bb=t1[tt*DIM+t]; h=fmaf(a,h,bb); p*=a; }
    Ag[sbase+t]=p; Bfg[sbase+t]=h;
  } else {
    int ch=t-128; float h=0.f;
    #pragma unroll 4
    for (int tt=CLEN-1;tt>=0;--tt){ h=fmaf(t0[tt*DIM+ch],h,t1[tt*DIM+ch]); }
    Bbg[sbase+ch]=h;
  }
}

// ------------------------------------------------ K2: prefix over chunk summaries
__global__ __launch_bounds__(128) void k_chunkscan(
    const float* __restrict__ Ag, const float* __restrict__ Bfg, const float* __restrict__ Bbg,
    float* __restrict__ Hf, float* __restrict__ Hb)
{
  const int dir = blockIdx.x >> 3, b = blockIdx.x & 7, ch = threadIdx.x;
  float s = 0.f;
  if (dir==0){
    for (int c=0;c<NCH;++c){ size_t i=((size_t)(b*NCH+c))*DIM+ch; Hf[i]=s; s=fmaf(Ag[i],s,Bfg[i]); }
  } else {
    for (int c=NCH-1;c>=0;--c){ size_t i=((size_t)(b*NCH+c))*DIM+ch; Hb[i]=s; s=fmaf(Ag[i],s,Bbg[i]); }
  }
}

// -------------------- K3: recompute a,b + seeded scan + MFMA out-proj + residual
__global__ __launch_bounds__(256,1) void k_scan(
    const float* __restrict__ xg, const float* __restrict__ w_in, const float* __restrict__ b_in,
    const float* __restrict__ pos, const float* __restrict__ w_i, const float* __restrict__ b_i,
    const float* __restrict__ w_r, const float* __restrict__ b_r, const float* __restrict__ avec,
    const float* __restrict__ aff,
    const float* __restrict__ Hf, const float* __restrict__ Hb,
    const u16* __restrict__ wot, const float* __restrict__ b_out,
    float* __restrict__ outg)
{
  __shared__ u16   wbuf[DIM*DIM];     // 32 KB
  __shared__ float t0[CLEN*DIM];      // 32 KB: a_t, then w_out chunk (u16)
  __shared__ float t1[CLEN*DIM];      // 32 KB: b_t
  __shared__ u16   hcat[CLEN*264];    // 33 KB, padded (264 = 256+8)
  const int t  = threadIdx.x;
  const int b  = blockIdx.x >> 7;
  const int ck = blockIdx.x & (NCH-1);
  const size_t base = ((size_t)(b*SEQ + ck*CLEN))*DIM;

  compute_ab(xg,w_in,b_in,pos,w_i,b_i,w_r,b_r,avec,aff,wbuf,t0,t1,b,ck,base,t);

  // seeded scans -> hcat
  const int pbase=(b*NCH+ck)*DIM;
  if (t<128){
    float h=Hf[pbase+t];
    #pragma unroll 4
    for (int tt=0;tt<CLEN;++tt){
      h=fmaf(t0[tt*DIM+t],h,t1[tt*DIM+t]);
      hcat[tt*264+t]=f2us(h);
    }
  } else {
    int ch=t-128;
    float h=Hb[pbase+ch];
    #pragma unroll 4
    for (int tt=CLEN-1;tt>=0;--tt){
      h=fmaf(t0[tt*DIM+ch],h,t1[tt*DIM+ch]);
      hcat[tt*264+128+ch]=f2us(h);
    }
  }
  __syncthreads();

  // MFMA out-proj: C[64][128] = hcat[64][256] @ w_out[256][128]
  const int lane=t&63, wv=t>>6, col=lane&15, quad=lane>>4;
  const int m0 = wv*16;
  u16* wol = (u16*)t0;                // [128][72] u16 = 18 KB (t0/t1 free now)
  f32x4 acc[8];
  #pragma unroll
  for (int n=0;n<8;++n) acc[n]=(f32x4){0.f,0.f,0.f,0.f};
  for (int chk=0; chk<4; ++chk){      // K-chunks of 64
    for (int i=t;i<1024;i+=256){      // 128 rows x 64 k = 1024 uint4
      int n=i>>3, c=(i&7)*8;
      *(uint4*)&wol[n*72 + c] = *(const uint4*)&wot[(size_t)n*256 + chk*64 + c];
    }
    __syncthreads();
    #pragma unroll
    for (int k2=0;k2<2;++k2){
      bf16x8 av = *(const bf16x8*)&hcat[(m0+col)*264 + chk*64 + k2*32 + quad*8];
      #pragma unroll
      for (int n=0;n<8;++n){
        bf16x8 bv = *(const bf16x8*)&wol[(n*16+col)*72 + k2*32 + quad*8];
        acc[n] = __builtin_amdgcn_mfma_f32_16x16x32_bf16(av, bv, acc[n], 0,0,0);
      }
    }
    __syncthreads();
  }
  const float g1=aff[b*6+2];
  #pragma unroll
  for (int n=0;n<8;++n){
    int nc = n*16 + col;
    float bo = b_out[nc];
    #pragma unroll
    for (int r=0;r<4;++r){
      int row = m0 + quad*4 + r;
      size_t gi = base + (size_t)row*DIM + nc;
      outg[gi] = fmaf(g1, acc[n][r]+bo, xg[gi]);
    }
  }
}

// -------------------- K4: cLN2 + MFMA gelu MLP + gated residual (116 KB LDS)
__global__ __launch_bounds__(256,1) void k_mlp(
    const u16* __restrict__ w1t, const float* __restrict__ b1v,
    const u16* __restrict__ w2t, const float* __restrict__ b2v,
    const float* __restrict__ aff, float* __restrict__ outg)
{
  __shared__ u16 h2l[CLEN*136];   // 17408 B, padded (136 = 128+8)
  __shared__ u16 wpl[128*136];    // 34816 B: w1 panel [128n][128k]; reused for w2 [128n][64k] pad->72
  __shared__ u16 m1l[CLEN*520];   // 66560 B, padded (520 = 512+8)
  const int t=threadIdx.x;
  const int b=blockIdx.x>>7;
  const size_t base=(size_t)blockIdx.x*CLEN*DIM;
  const int lane=t&63, wv=t>>6, col=lane&15, quad=lane>>4;
  const int m0 = wv*16;
  const float s2p=1.f+aff[b*6+3], b2a=aff[b*6+4], g2=aff[b*6+5];

  // step 0: h2 = (1+s2)*LN(x1)+b2 -> h2l (bf16)
  {
    const int cg=t&15, rg=t>>4, j0=cg*8, r0=rg*4;
    #pragma unroll
    for (int ii=0;ii<4;++ii){
      int r=r0+ii;
      const float* xo = outg + base + (size_t)r*DIM + j0;
      float4 a = *(const float4*)xo;
      float4 bq = *(const float4*)(xo+4);
      float o[8]={a.x,a.y,a.z,a.w,bq.x,bq.y,bq.z,bq.w};
      float s=0.f;
      #pragma unroll
      for (int j=0;j<8;++j) s+=o[j];
      s=red16(s); float m=s*(1.f/128.f);
      float q2=0.f;
      #pragma unroll
      for (int j=0;j<8;++j){ float d=o[j]-m; q2+=d*d; }
      q2=red16(q2); float rs=rsqrtf(q2*(1.f/128.f)+1e-6f);
      u32 pk[4];
      #pragma unroll
      for (int q=0;q<4;++q){
        float a0=fmaf((o[2*q]-m)*rs,   s2p, b2a);
        float a1=fmaf((o[2*q+1]-m)*rs, s2p, b2a);
        pk[q]= (u32)f2us(a0) | ((u32)f2us(a1)<<16);
      }
      *(uint4*)&h2l[r*136+j0] = make_uint4(pk[0],pk[1],pk[2],pk[3]);
    }
  }
  __syncthreads();

  // ---- mm1: C1[64][512] = h2 @ w1, gelu -> m1l ----
  f32x4 acc[8];
  for (int p=0;p<4;++p){              // N-panels of 128 cols
    for (int i=t;i<2048;i+=256){      // 128 rows x 128 k = 2048 uint4
      int n=i>>4, c=(i&15)*8;
      *(uint4*)&wpl[n*136 + c] = *(const uint4*)&w1t[(size_t)(p*128+n)*128 + c];
    }
    __syncthreads();
    #pragma unroll
    for (int n=0;n<8;++n) acc[n]=(f32x4){0.f,0.f,0.f,0.f};
    #pragma unroll
    for (int kk=0;kk<4;++kk){
      bf16x8 av = *(const bf16x8*)&h2l[(m0+col)*136 + kk*32 + quad*8];
      #pragma unroll
      for (int n=0;n<8;++n){
        bf16x8 bv = *(const bf16x8*)&wpl[(n*16+col)*136 + kk*32 + quad*8];
        acc[n] = __builtin_amdgcn_mfma_f32_16x16x32_bf16(av, bv, acc[n], 0,0,0);
      }
    }
    #pragma unroll
    for (int n=0;n<8;++n){
      int nc = p*128 + n*16 + col;
      float bb = b1v[nc];
      #pragma unroll
      for (int r=0;r<4;++r){
        int row = m0 + quad*4 + r;
        m1l[row*520 + nc] = f2us(gelu_tanh(acc[n][r] + bb));
      }
    }
    __syncthreads();
  }

  // ---- mm2: C2[64][128] = m1 @ w2 ----
  u16* w2l = wpl;                     // [128][72]
  f32x4 acc2[8];
  #pragma unroll
  for (int n=0;n<8;++n) acc2[n]=(f32x4){0.f,0.f,0.f,0.f};
  for (int chk=0;chk<8;++chk){        // K-chunks of 64
    for (int i=t;i<1024;i+=256){
      int n=i>>3, c=(i&7)*8;
      *(uint4*)&w2l[n*72 + c] = *(const uint4*)&w2t[(size_t)n*512 + chk*64 + c];
    }
    __syncthreads();
    #pragma unroll
    for (int k2=0;k2<2;++k2){
      bf16x8 av = *(const bf16x8*)&m1l[(m0+col)*520 + chk*64 + k2*32 + quad*8];
      #pragma unroll
      for (int n=0;n<8;++n){
        bf16x8 bv = *(const bf16x8*)&w2l[(n*16+col)*72 + k2*32 + quad*8];
        acc2[n] = __builtin_amdgcn_mfma_f32_16x16x32_bf16(av, bv, acc2[n], 0,0,0);
      }
    }
    __syncthreads();
  }
  // epilogue: out = x1 + g2*(C2 + b2)
  #pragma unroll
  for (int n=0;n<8;++n){
    int nc = n*16 + col;
    float bb = b2v[nc];
    #pragma unroll
    for (int r=0;r<4;++r){
      int row = m0 + quad*4 + r;
      size_t gi = base + (size_t)row*DIM + nc;
      outg[gi] = fmaf(g2, acc2[n][r] + bb, outg[gi]);
    }
  }
}

// ----------------------------------------------------------------------------
extern "C" void kernel_launch(void* const* d_in, const int* in_sizes, int n_in,
                              void* d_out, int out_size, void* d_ws, size_t ws_size,
                              hipStream_t stream)
{
  (void)in_sizes; (void)n_in; (void)out_size; (void)ws_size;
  const float* x   =(const float*)d_in[0];
  const float* c   =(const float*)d_in[1];
  const float* c1sw=(const float*)d_in[2];  const float* c1sb=(const float*)d_in[3];
  const float* c1bw=(const float*)d_in[4];  const float* c1bb=(const float*)d_in[5];
  const float* g1w =(const float*)d_in[6];  const float* g1b =(const float*)d_in[7];
  const float* win =(const float*)d_in[8];  const float* binv=(const float*)d_in[9];
  const float* pos =(const float*)d_in[10];
  const float* wi  =(const float*)d_in[11]; const float* biv =(const float*)d_in[12];
  const float* wr  =(const float*)d_in[13]; const float* brv =(const float*)d_in[14];
  const float* av  =(const float*)d_in[15];
  const float* wout=(const float*)d_in[16]; const float* bout=(const float*)d_in[17];
  const float* c2sw=(const float*)d_in[18]; const float* c2sb=(const float*)d_in[19];
  const float* c2bw=(const float*)d_in[20]; const float* c2bb=(const float*)d_in[21];
  const float* g2w =(const float*)d_in[22]; const float* g2b =(const float*)d_in[23];
  const float* w1  =(const float*)d_in[24]; const float* b1v =(const float*)d_in[25];
  const float* w2  =(const float*)d_in[26]; const float* b2v =(const float*)d_in[27];

  // workspace: 2.62 MB scan state + 320 KB bf16 transposed weights
  float* wsf  = (float*)d_ws;
  float* Ag   = wsf;
  float* Bfg  = Ag   + 131072;
  float* Bbg  = Bfg  + 131072;
  float* Hf   = Bbg  + 131072;
  float* Hb   = Hf   + 131072;
  float* aff  = Hb   + 131072;       // 48 (pad 64)
  u16*   w1t  = (u16*)(aff + 64);    // [512][128]
  u16*   w2t  = w1t + 65536;         // [128][512]
  u16*   wot  = w2t + 65536;         // [128][256]

  float* outg = (float*)d_out;

  k_aff<<<dim3(1),dim3(64),0,stream>>>(c, c1sw,c1bw,g1w,c2sw,c2bw,g2w,
                                       c1sb,c1bb,g1b,c2sb,c2bb,g2b, aff);
  k_prep<<<dim3(256),dim3(256),0,stream>>>(w1,w2,wout, w1t,w2t,wot);
  k_pre<<<dim3(BSZ*NCH),dim3(256),0,stream>>>(x,win,binv,pos,wi,biv,wr,brv,av,aff,
                                              Ag,Bfg,Bbg);
  k_chunkscan<<<dim3(16),dim3(128),0,stream>>>(Ag,Bfg,Bbg,Hf,Hb);
  k_scan<<<dim3(BSZ*NCH),dim3(256),0,stream>>>(x,win,binv,pos,wi,biv,wr,brv,av,aff,
                                               Hf,Hb,wot,bout,outg);
  k_mlp<<<dim3(BSZ*NCH),dim3(256),0,stream>>>(w1t,b1v,w2t,b2v,aff,outg);
}

// Round 7
// 383.291 us; speedup vs baseline: 3.3320x; 1.8998x over previous
//
#include <hip/hip_runtime.h>
#include <hip/hip_bf16.h>

#define BSZ 8
#define SEQ 8192
#define DIM 128
#define NCH 128   // chunks per sequence
#define CLEN 64   // tokens per chunk

typedef unsigned short u16;
typedef unsigned int u32;
typedef short bf16x8 __attribute__((ext_vector_type(8)));
typedef float f32x4  __attribute__((ext_vector_type(4)));

__device__ __forceinline__ float us2f(u16 w){ union{u32 i;float f;}u; u.i=((u32)w)<<16; return u.f; }
__device__ __forceinline__ u16 f2us(float f){
  __hip_bfloat16 h = __float2bfloat16(f);
  union{ __hip_bfloat16 b; u16 s; }u; u.b=h; return u.s;
}
__device__ __forceinline__ float wred64(float v){
  #pragma unroll
  for (int o=1;o<64;o<<=1) v += __shfl_xor(v,o,64);
  return v;
}
__device__ __forceinline__ float red16(float v){
  v += __shfl_xor(v,1,64); v += __shfl_xor(v,2,64);
  v += __shfl_xor(v,4,64); v += __shfl_xor(v,8,64);
  return v;
}
__device__ __forceinline__ float sigmoidf_(float z){ return 1.f/(1.f+__expf(-z)); }
__device__ __forceinline__ float gelu_tanh(float x){
  float y = 0.7978845608028654f * fmaf(0.044715f*x, x*x, x);
  float e = __expf(2.f*y);
  float th = 1.f - 2.f/(e+1.f);
  return 0.5f*x*(1.f+th);
}

// ---------------------------------------------------------------- K0: affines
__global__ __launch_bounds__(64) void k_aff(
    const float* __restrict__ c,
    const float* w0,const float* w1,const float* w2,const float* w3,const float* w4,const float* w5,
    const float* s0,const float* s1,const float* s2,const float* s3,const float* s4,const float* s5,
    float* __restrict__ aff)
{
  const float* ws[6]={w0,w1,w2,w3,w4,w5};
  const float* bs[6]={s0,s1,s2,s3,s4,s5};
  int l = threadIdx.x;
  for (int b=0;b<BSZ;++b){
    #pragma unroll
    for (int h=0;h<6;++h){
      float v = c[b*128+l]*ws[h][l] + c[b*128+64+l]*ws[h][64+l];
      v = wred64(v);
      if (l==0) aff[b*6+h] = v + bs[h][0];
    }
  }
}

// ------------------------------------------- K0b: weight transposes fp32->bf16 [N][K]
__global__ __launch_bounds__(256) void k_prep(
    const float* __restrict__ w1, const float* __restrict__ w2, const float* __restrict__ wo,
    const float* __restrict__ win, const float* __restrict__ wi, const float* __restrict__ wr,
    u16* __restrict__ w1t, u16* __restrict__ w2t, u16* __restrict__ wot,
    u16* __restrict__ wint, u16* __restrict__ wit, u16* __restrict__ wrt)
{
  int i = blockIdx.x*256 + threadIdx.x;          // 65536 threads
  { int n=i>>7, k=i&127; w1t[i] = f2us(w1[k*512+n]); }
  { int n=i>>9, k=i&511; w2t[i] = f2us(w2[k*128+n]); }
  if (i < 32768){ int n=i>>8, k=i&255; wot[i] = f2us(wo[k*128+n]); }
  if (i < 16384){
    int n=i>>7, k=i&127;
    wint[i] = f2us(win[k*128+n]);
    wit[i]  = f2us(wi[k*128+n]);
    wrt[i]  = f2us(wr[k*128+n]);
  }
}

// -------------------- K1: LN + MFMA gates -> a_t,b_t (global bf16) + chunk summaries
__global__ __launch_bounds__(256,1) void k_pre(
    const float* __restrict__ xg, const u16* __restrict__ wint, const float* __restrict__ b_in,
    const float* __restrict__ pos, const u16* __restrict__ wit, const float* __restrict__ b_i,
    const u16* __restrict__ wrt, const float* __restrict__ b_r, const float* __restrict__ avec,
    const float* __restrict__ aff,
    u16* __restrict__ atg, u16* __restrict__ btg,
    float* __restrict__ Ag, float* __restrict__ Bfg, float* __restrict__ Bbg)
{
  __shared__ u16   A_l[CLEN*136];   // 17.4 KB: lnh, then u (bf16, A-operand layout)
  __shared__ u16   wT[128*136];     // 34.8 KB: one transposed weight at a time
  __shared__ float t0[CLEN*DIM];    // 32 KB: a_t
  __shared__ float t1[CLEN*DIM];    // 32 KB: b_t
  const int t  = threadIdx.x;
  const int b  = blockIdx.x >> 7;
  const int ck = blockIdx.x & (NCH-1);
  const size_t base = ((size_t)(b*SEQ + ck*CLEN))*DIM;
  const int lane=t&63, wv=t>>6, col=lane&15, quad=lane>>4;
  const int m0 = wv*16;

  // stage w_in^T
  for (int i=t;i<2048;i+=256){
    int n=i>>4, c=(i&15)*8;
    *(uint4*)&wT[n*136+c] = *(const uint4*)&wint[(size_t)n*128 + c];
  }

  // LN: lnh = z * (1+s1)*rsqrt((1+s1)^2 * v/(v+eps) + eps), z=(x-m)*rsqrt(v+eps)
  {
    const float s1p = 1.f + aff[b*6+0];
    const int ln = t&63;
    for (int i=0;i<16;++i){
      int r = wv*16 + i;
      float2 v = *(const float2*)(xg + base + (size_t)r*DIM + 2*ln);
      float m  = wred64(v.x+v.y)*(1.f/128.f);
      float d0=v.x-m, d1=v.y-m;
      float var = wred64(d0*d0+d1*d1)*(1.f/128.f);
      float rs = rsqrtf(var + 1e-6f);
      float vz = var*rs*rs;                               // v/(v+eps)
      float tt2 = s1p*rsqrtf(fmaf(s1p*s1p, vz, 1e-6f));
      float sc = rs*tt2;
      u32 pk = (u32)f2us(d0*sc) | ((u32)f2us(d1*sc)<<16);
      *(u32*)&A_l[r*136 + 2*ln] = pk;
    }
  }
  __syncthreads();

  // mm B: u = lnh @ w_in  (+ b_in + pos)
  f32x4 uacc[8];
  #pragma unroll
  for (int n=0;n<8;++n) uacc[n]=(f32x4){0.f,0.f,0.f,0.f};
  #pragma unroll
  for (int kk=0;kk<4;++kk){
    bf16x8 av = *(const bf16x8*)&A_l[(m0+col)*136 + kk*32 + quad*8];
    #pragma unroll
    for (int n=0;n<8;++n){
      bf16x8 bv = *(const bf16x8*)&wT[(n*16+col)*136 + kk*32 + quad*8];
      uacc[n] = __builtin_amdgcn_mfma_f32_16x16x32_bf16(av, bv, uacc[n], 0,0,0);
    }
  }
  float u_c[8][4];
  #pragma unroll
  for (int n=0;n<8;++n){
    int nc = n*16 + col;
    float bi = b_in[nc];
    #pragma unroll
    for (int r=0;r<4;++r){
      int row = m0 + quad*4 + r;
      u_c[n][r] = uacc[n][r] + bi + pos[(size_t)(ck*CLEN+row)*DIM + nc];
    }
  }
  __syncthreads();     // done reading lnh (A_l) and wT

  // write u (bf16) into A_l; stage w_i^T
  #pragma unroll
  for (int n=0;n<8;++n){
    #pragma unroll
    for (int r=0;r<4;++r)
      A_l[(m0+quad*4+r)*136 + n*16+col] = f2us(u_c[n][r]);
  }
  for (int i=t;i<2048;i+=256){
    int n=i>>4, c=(i&15)*8;
    *(uint4*)&wT[n*136+c] = *(const uint4*)&wit[(size_t)n*128 + c];
  }
  __syncthreads();

  // mm C: gi = sigmoid(u @ w_i + b_i)
  f32x4 gacc[8];
  #pragma unroll
  for (int n=0;n<8;++n) gacc[n]=(f32x4){0.f,0.f,0.f,0.f};
  #pragma unroll
  for (int kk=0;kk<4;++kk){
    bf16x8 av = *(const bf16x8*)&A_l[(m0+col)*136 + kk*32 + quad*8];
    #pragma unroll
    for (int n=0;n<8;++n){
      bf16x8 bv = *(const bf16x8*)&wT[(n*16+col)*136 + kk*32 + quad*8];
      gacc[n] = __builtin_amdgcn_mfma_f32_16x16x32_bf16(av, bv, gacc[n], 0,0,0);
    }
  }
  float gi_c[8][4];
  #pragma unroll
  for (int n=0;n<8;++n){
    float bi = b_i[n*16+col];
    #pragma unroll
    for (int r=0;r<4;++r) gi_c[n][r] = sigmoidf_(gacc[n][r]+bi);
  }
  __syncthreads();     // done reading wT

  // stage w_r^T
  for (int i=t;i<2048;i+=256){
    int n=i>>4, c=(i&15)*8;
    *(uint4*)&wT[n*136+c] = *(const uint4*)&wrt[(size_t)n*128 + c];
  }
  __syncthreads();

  // mm D: gr
  f32x4 racc[8];
  #pragma unroll
  for (int n=0;n<8;++n) racc[n]=(f32x4){0.f,0.f,0.f,0.f};
  #pragma unroll
  for (int kk=0;kk<4;++kk){
    bf16x8 av = *(const bf16x8*)&A_l[(m0+col)*136 + kk*32 + quad*8];
    #pragma unroll
    for (int n=0;n<8;++n){
      bf16x8 bv = *(const bf16x8*)&wT[(n*16+col)*136 + kk*32 + quad*8];
      racc[n] = __builtin_amdgcn_mfma_f32_16x16x32_bf16(av, bv, racc[n], 0,0,0);
    }
  }

  // a_t, b_t -> LDS (fp32) + global (bf16)
  #pragma unroll
  for (int n=0;n<8;++n){
    int nc = n*16 + col;
    float la = __logf(avec[nc]);
    float br = b_r[nc];
    #pragma unroll
    for (int r=0;r<4;++r){
      int row = m0 + quad*4 + r;
      float g = sigmoidf_(racc[n][r]+br);
      float a = __expf(8.f*g*la);
      float bb = sqrtf(fmaxf(1.f-a*a,0.f))*gi_c[n][r]*u_c[n][r];
      t0[row*DIM+nc]=a; t1[row*DIM+nc]=bb;
      atg[base + (size_t)row*DIM + nc] = f2us(a);
      btg[base + (size_t)row*DIM + nc] = f2us(bb);
    }
  }
  __syncthreads();

  // chunk-local scans -> summaries
  const int sbase = (b*NCH+ck)*DIM;
  if (t < 128){
    float h=0.f, p=1.f;
    #pragma unroll 4
    for (int tt=0;tt<CLEN;++tt){ float a=t0[tt*DIM+t], bb=t1[tt*DIM+t]; h=fmaf(a,h,bb); p*=a; }
    Ag[sbase+t]=p; Bfg[sbase+t]=h;
  } else {
    int ch=t-128; float h=0.f;
    #pragma unroll 4
    for (int tt=CLEN-1;tt>=0;--tt){ h=fmaf(t0[tt*DIM+ch],h,t1[tt*DIM+ch]); }
    Bbg[sbase+ch]=h;
  }
}

// ------------------------------------------------ K2: prefix over chunk summaries
__global__ __launch_bounds__(128) void k_chunkscan(
    const float* __restrict__ Ag, const float* __restrict__ Bfg, const float* __restrict__ Bbg,
    float* __restrict__ Hf, float* __restrict__ Hb)
{
  const int dir = blockIdx.x >> 3, b = blockIdx.x & 7, ch = threadIdx.x;
  float s = 0.f;
  if (dir==0){
    for (int c=0;c<NCH;++c){ size_t i=((size_t)(b*NCH+c))*DIM+ch; Hf[i]=s; s=fmaf(Ag[i],s,Bfg[i]); }
  } else {
    for (int c=NCH-1;c>=0;--c){ size_t i=((size_t)(b*NCH+c))*DIM+ch; Hb[i]=s; s=fmaf(Ag[i],s,Bbg[i]); }
  }
}

// -------------------- K3: load a,b + seeded scan + MFMA out-proj + residual (65 KB LDS)
__global__ __launch_bounds__(256,2) void k_scan(
    const u16* __restrict__ atg, const u16* __restrict__ btg,
    const float* __restrict__ Hf, const float* __restrict__ Hb,
    const float* __restrict__ xg, const u16* __restrict__ wot, const float* __restrict__ b_out,
    const float* __restrict__ aff, float* __restrict__ outg)
{
  __shared__ u16 sm[CLEN*DIM*2];    // 32 KB: a_l | b_l ; reused as wol [128][72]
  __shared__ u16 hcat[CLEN*264];    // 33 KB
  u16* a_l = sm;
  u16* b_l = sm + CLEN*DIM;
  const int t  = threadIdx.x;
  const int b  = blockIdx.x >> 7;
  const int ck = blockIdx.x & (NCH-1);
  const size_t base = ((size_t)(b*SEQ + ck*CLEN))*DIM;

  {
    const uint4* sa=(const uint4*)(atg+base); const uint4* sb=(const uint4*)(btg+base);
    for (int i=t;i<1024;i+=256){ ((uint4*)a_l)[i]=sa[i]; ((uint4*)b_l)[i]=sb[i]; }
  }
  __syncthreads();

  // seeded scans -> hcat
  const int pbase=(b*NCH+ck)*DIM;
  if (t<128){
    float h=Hf[pbase+t];
    #pragma unroll 4
    for (int tt=0;tt<CLEN;++tt){
      h=fmaf(us2f(a_l[tt*DIM+t]),h,us2f(b_l[tt*DIM+t]));
      hcat[tt*264+t]=f2us(h);
    }
  } else {
    int ch=t-128;
    float h=Hb[pbase+ch];
    #pragma unroll 4
    for (int tt=CLEN-1;tt>=0;--tt){
      h=fmaf(us2f(a_l[tt*DIM+ch]),h,us2f(b_l[tt*DIM+ch]));
      hcat[tt*264+128+ch]=f2us(h);
    }
  }
  __syncthreads();

  // MFMA out-proj: C[64][128] = hcat[64][256] @ w_out[256][128]
  const int lane=t&63, wv=t>>6, col=lane&15, quad=lane>>4;
  const int m0 = wv*16;
  u16* wol = sm;                      // [128][72], overlaps a_l/b_l (free now)
  f32x4 acc[8];
  #pragma unroll
  for (int n=0;n<8;++n) acc[n]=(f32x4){0.f,0.f,0.f,0.f};
  for (int chk=0; chk<4; ++chk){      // K-chunks of 64
    for (int i=t;i<1024;i+=256){
      int n=i>>3, c=(i&7)*8;
      *(uint4*)&wol[n*72 + c] = *(const uint4*)&wot[(size_t)n*256 + chk*64 + c];
    }
    __syncthreads();
    #pragma unroll
    for (int k2=0;k2<2;++k2){
      bf16x8 av = *(const bf16x8*)&hcat[(m0+col)*264 + chk*64 + k2*32 + quad*8];
      #pragma unroll
      for (int n=0;n<8;++n){
        bf16x8 bv = *(const bf16x8*)&wol[(n*16+col)*72 + k2*32 + quad*8];
        acc[n] = __builtin_amdgcn_mfma_f32_16x16x32_bf16(av, bv, acc[n], 0,0,0);
      }
    }
    __syncthreads();
  }
  const float g1=aff[b*6+2];
  #pragma unroll
  for (int n=0;n<8;++n){
    int nc = n*16 + col;
    float bo = b_out[nc];
    #pragma unroll
    for (int r=0;r<4;++r){
      int row = m0 + quad*4 + r;
      size_t gi = base + (size_t)row*DIM + nc;
      outg[gi] = fmaf(g1, acc[n][r]+bo, xg[gi]);
    }
  }
}

// -------------------- K4: cLN2 + MFMA gelu MLP + gated residual (116 KB LDS)
__global__ __launch_bounds__(256,1) void k_mlp(
    const u16* __restrict__ w1t, const float* __restrict__ b1v,
    const u16* __restrict__ w2t, const float* __restrict__ b2v,
    const float* __restrict__ aff, float* __restrict__ outg)
{
  __shared__ u16 h2l[CLEN*136];   // 17408 B
  __shared__ u16 wpl[128*136];    // 34816 B
  __shared__ u16 m1l[CLEN*520];   // 66560 B
  const int t=threadIdx.x;
  const int b=blockIdx.x>>7;
  const size_t base=(size_t)blockIdx.x*CLEN*DIM;
  const int lane=t&63, wv=t>>6, col=lane&15, quad=lane>>4;
  const int m0 = wv*16;
  const float s2p=1.f+aff[b*6+3], b2a=aff[b*6+4], g2=aff[b*6+5];

  // step 0: h2 = (1+s2)*LN(x1)+b2 -> h2l (bf16)
  {
    const int cg=t&15, rg=t>>4, j0=cg*8, r0=rg*4;
    #pragma unroll
    for (int ii=0;ii<4;++ii){
      int r=r0+ii;
      const float* xo = outg + base + (size_t)r*DIM + j0;
      float4 a = *(const float4*)xo;
      float4 bq = *(const float4*)(xo+4);
      float o[8]={a.x,a.y,a.z,a.w,bq.x,bq.y,bq.z,bq.w};
      float s=0.f;
      #pragma unroll
      for (int j=0;j<8;++j) s+=o[j];
      s=red16(s); float m=s*(1.f/128.f);
      float q2=0.f;
      #pragma unroll
      for (int j=0;j<8;++j){ float d=o[j]-m; q2+=d*d; }
      q2=red16(q2); float rs=rsqrtf(q2*(1.f/128.f)+1e-6f);
      u32 pk[4];
      #pragma unroll
      for (int q=0;q<4;++q){
        float a0=fmaf((o[2*q]-m)*rs,   s2p, b2a);
        float a1=fmaf((o[2*q+1]-m)*rs, s2p, b2a);
        pk[q]= (u32)f2us(a0) | ((u32)f2us(a1)<<16);
      }
      *(uint4*)&h2l[r*136+j0] = make_uint4(pk[0],pk[1],pk[2],pk[3]);
    }
  }
  __syncthreads();

  // ---- mm1: C1[64][512] = h2 @ w1, gelu -> m1l ----
  f32x4 acc[8];
  for (int p=0;p<4;++p){              // N-panels of 128 cols
    for (int i=t;i<2048;i+=256){
      int n=i>>4, c=(i&15)*8;
      *(uint4*)&wpl[n*136 + c] = *(const uint4*)&w1t[(size_t)(p*128+n)*128 + c];
    }
    __syncthreads();
    #pragma unroll
    for (int n=0;n<8;++n) acc[n]=(f32x4){0.f,0.f,0.f,0.f};
    #pragma unroll
    for (int kk=0;kk<4;++kk){
      bf16x8 av = *(const bf16x8*)&h2l[(m0+col)*136 + kk*32 + quad*8];
      #pragma unroll
      for (int n=0;n<8;++n){
        bf16x8 bv = *(const bf16x8*)&wpl[(n*16+col)*136 + kk*32 + quad*8];
        acc[n] = __builtin_amdgcn_mfma_f32_16x16x32_bf16(av, bv, acc[n], 0,0,0);
      }
    }
    #pragma unroll
    for (int n=0;n<8;++n){
      int nc = p*128 + n*16 + col;
      float bb = b1v[nc];
      #pragma unroll
      for (int r=0;r<4;++r){
        int row = m0 + quad*4 + r;
        m1l[row*520 + nc] = f2us(gelu_tanh(acc[n][r] + bb));
      }
    }
    __syncthreads();
  }

  // ---- mm2: C2[64][128] = m1 @ w2 ----
  u16* w2l = wpl;                     // [128][72]
  f32x4 acc2[8];
  #pragma unroll
  for (int n=0;n<8;++n) acc2[n]=(f32x4){0.f,0.f,0.f,0.f};
  for (int chk=0;chk<8;++chk){        // K-chunks of 64
    for (int i=t;i<1024;i+=256){
      int n=i>>3, c=(i&7)*8;
      *(uint4*)&w2l[n*72 + c] = *(const uint4*)&w2t[(size_t)n*512 + chk*64 + c];
    }
    __syncthreads();
    #pragma unroll
    for (int k2=0;k2<2;++k2){
      bf16x8 av = *(const bf16x8*)&m1l[(m0+col)*520 + chk*64 + k2*32 + quad*8];
      #pragma unroll
      for (int n=0;n<8;++n){
        bf16x8 bv = *(const bf16x8*)&w2l[(n*16+col)*72 + k2*32 + quad*8];
        acc2[n] = __builtin_amdgcn_mfma_f32_16x16x32_bf16(av, bv, acc2[n], 0,0,0);
      }
    }
    __syncthreads();
  }
  // epilogue: out = x1 + g2*(C2 + b2)
  #pragma unroll
  for (int n=0;n<8;++n){
    int nc = n*16 + col;
    float bb = b2v[nc];
    #pragma unroll
    for (int r=0;r<4;++r){
      int row = m0 + quad*4 + r;
      size_t gi = base + (size_t)row*DIM + nc;
      outg[gi] = fmaf(g2, acc2[n][r] + bb, outg[gi]);
    }
  }
}

// ----------------------------------------------------------------------------
extern "C" void kernel_launch(void* const* d_in, const int* in_sizes, int n_in,
                              void* d_out, int out_size, void* d_ws, size_t ws_size,
                              hipStream_t stream)
{
  (void)in_sizes; (void)n_in; (void)out_size; (void)ws_size;
  const float* x   =(const float*)d_in[0];
  const float* c   =(const float*)d_in[1];
  const float* c1sw=(const float*)d_in[2];  const float* c1sb=(const float*)d_in[3];
  const float* c1bw=(const float*)d_in[4];  const float* c1bb=(const float*)d_in[5];
  const float* g1w =(const float*)d_in[6];  const float* g1b =(const float*)d_in[7];
  const float* win =(const float*)d_in[8];  const float* binv=(const float*)d_in[9];
  const float* pos =(const float*)d_in[10];
  const float* wi  =(const float*)d_in[11]; const float* biv =(const float*)d_in[12];
  const float* wr  =(const float*)d_in[13]; const float* brv =(const float*)d_in[14];
  const float* av  =(const float*)d_in[15];
  const float* wout=(const float*)d_in[16]; const float* bout=(const float*)d_in[17];
  const float* c2sw=(const float*)d_in[18]; const float* c2sb=(const float*)d_in[19];
  const float* c2bw=(const float*)d_in[20]; const float* c2bb=(const float*)d_in[21];
  const float* g2w =(const float*)d_in[22]; const float* g2b =(const float*)d_in[23];
  const float* w1  =(const float*)d_in[24]; const float* b1v =(const float*)d_in[25];
  const float* w2  =(const float*)d_in[26]; const float* b2v =(const float*)d_in[27];

  // workspace layout (~36.6 MB total)
  float* wsf  = (float*)d_ws;
  float* Ag   = wsf;
  float* Bfg  = Ag   + 131072;
  float* Bbg  = Bfg  + 131072;
  float* Hf   = Bbg  + 131072;
  float* Hb   = Hf   + 131072;
  float* aff  = Hb   + 131072;       // 48 (pad 64)
  u16*   w1t  = (u16*)(aff + 64);    // [512][128]
  u16*   w2t  = w1t + 65536;         // [128][512]
  u16*   wot  = w2t + 65536;         // [128][256]
  u16*   wint = wot + 32768;         // [128][128]
  u16*   wit  = wint + 16384;
  u16*   wrt  = wit  + 16384;
  u16*   atg  = wrt  + 16384;        // [BSZ*SEQ*DIM] bf16
  u16*   btg  = atg  + 8388608;

  float* outg = (float*)d_out;

  k_aff<<<dim3(1),dim3(64),0,stream>>>(c, c1sw,c1bw,g1w,c2sw,c2bw,g2w,
                                       c1sb,c1bb,g1b,c2sb,c2bb,g2b, aff);
  k_prep<<<dim3(256),dim3(256),0,stream>>>(w1,w2,wout,win,wi,wr,
                                           w1t,w2t,wot,wint,wit,wrt);
  k_pre<<<dim3(BSZ*NCH),dim3(256),0,stream>>>(x,wint,binv,pos,wit,biv,wrt,brv,av,aff,
                                              atg,btg, Ag,Bfg,Bbg);
  k_chunkscan<<<dim3(16),dim3(128),0,stream>>>(Ag,Bfg,Bbg,Hf,Hb);
  k_scan<<<dim3(BSZ*NCH),dim3(256),0,stream>>>(atg,btg,Hf,Hb,x,wot,bout,aff,outg);
  k_mlp<<<dim3(BSZ*NCH),dim3(256),0,stream>>>(w1t,b1v,w2t,b2v,aff,outg);
}

// Round 8
// 329.740 us; speedup vs baseline: 3.8731x; 1.1624x over previous
//
#include <hip/hip_runtime.h>
#include <hip/hip_bf16.h>

#define BSZ 8
#define SEQ 8192
#define DIM 128
#define NCH 128   // chunks per sequence
#define CLEN 64   // tokens per chunk

typedef unsigned short u16;
typedef unsigned int u32;
typedef short bf16x8 __attribute__((ext_vector_type(8)));
typedef float f32x4  __attribute__((ext_vector_type(4)));

__device__ __forceinline__ float us2f(u16 w){ union{u32 i;float f;}u; u.i=((u32)w)<<16; return u.f; }
__device__ __forceinline__ u16 f2us(float f){
  __hip_bfloat16 h = __float2bfloat16(f);
  union{ __hip_bfloat16 b; u16 s; }u; u.b=h; return u.s;
}
__device__ __forceinline__ float wred64(float v){
  #pragma unroll
  for (int o=1;o<64;o<<=1) v += __shfl_xor(v,o,64);
  return v;
}
__device__ __forceinline__ float red16(float v){
  v += __shfl_xor(v,1,64); v += __shfl_xor(v,2,64);
  v += __shfl_xor(v,4,64); v += __shfl_xor(v,8,64);
  return v;
}
__device__ __forceinline__ float sigmoidf_(float z){ return 1.f/(1.f+__expf(-z)); }
__device__ __forceinline__ float gelu_tanh(float x){
  float y = 0.7978845608028654f * fmaf(0.044715f*x, x*x, x);
  float e = __expf(2.f*y);
  float th = 1.f - 2.f/(e+1.f);
  return 0.5f*x*(1.f+th);
}

// ---------------------------------------------------------------- K0: affines
__global__ __launch_bounds__(64) void k_aff(
    const float* __restrict__ c,
    const float* w0,const float* w1,const float* w2,const float* w3,const float* w4,const float* w5,
    const float* s0,const float* s1,const float* s2,const float* s3,const float* s4,const float* s5,
    float* __restrict__ aff)
{
  const float* ws[6]={w0,w1,w2,w3,w4,w5};
  const float* bs[6]={s0,s1,s2,s3,s4,s5};
  int l = threadIdx.x;
  for (int b=0;b<BSZ;++b){
    #pragma unroll
    for (int h=0;h<6;++h){
      float v = c[b*128+l]*ws[h][l] + c[b*128+64+l]*ws[h][64+l];
      v = wred64(v);
      if (l==0) aff[b*6+h] = v + bs[h][0];
    }
  }
}

// ------------------------------------------- K0b: weight transposes fp32->bf16 [N][K]
__global__ __launch_bounds__(256) void k_prep(
    const float* __restrict__ w1, const float* __restrict__ w2, const float* __restrict__ wo,
    const float* __restrict__ win, const float* __restrict__ wi, const float* __restrict__ wr,
    u16* __restrict__ w1t, u16* __restrict__ w2t, u16* __restrict__ wot,
    u16* __restrict__ wint, u16* __restrict__ wit, u16* __restrict__ wrt)
{
  int i = blockIdx.x*256 + threadIdx.x;          // 65536 threads
  { int n=i>>7, k=i&127; w1t[i] = f2us(w1[k*512+n]); }
  { int n=i>>9, k=i&511; w2t[i] = f2us(w2[k*128+n]); }
  if (i < 32768){ int n=i>>8, k=i&255; wot[i] = f2us(wo[k*128+n]); }
  if (i < 16384){
    int n=i>>7, k=i&127;
    wint[i] = f2us(win[k*128+n]);
    wit[i]  = f2us(wi[k*128+n]);
    wrt[i]  = f2us(wr[k*128+n]);
  }
}

// -------------------- K1: LN + MFMA gates -> a_t,b_t (bf16) + chunk summaries (67 KB LDS)
__global__ __launch_bounds__(256,2) void k_pre(
    const float* __restrict__ xg, const u16* __restrict__ wint, const float* __restrict__ b_in,
    const float* __restrict__ pos, const u16* __restrict__ wit, const float* __restrict__ b_i,
    const u16* __restrict__ wrt, const float* __restrict__ b_r, const float* __restrict__ avec,
    const float* __restrict__ aff,
    u16* __restrict__ atg, u16* __restrict__ btg,
    float* __restrict__ Ag, float* __restrict__ Bfg, float* __restrict__ Bbg)
{
  __shared__ u16 A_l[CLEN*136];   // 17.4 KB: lnh, then u (A-operand layout)
  __shared__ u16 wT[128*72];      // 18.4 KB: one 64-K chunk of a transposed weight
  __shared__ u32 abp[CLEN*DIM];   // 32 KB: packed (a_bf16 | b_bf16<<16)
  const int t  = threadIdx.x;
  const int b  = blockIdx.x >> 7;
  const int ck = blockIdx.x & (NCH-1);
  const size_t base = ((size_t)(b*SEQ + ck*CLEN))*DIM;
  const int lane=t&63, wv=t>>6, col=lane&15, quad=lane>>4;
  const int m0 = wv*16;

  // LN: lnh = z * (1+s1)*rsqrt((1+s1)^2 * v/(v+eps) + eps), z=(x-m)*rsqrt(v+eps)
  {
    const float s1p = 1.f + aff[b*6+0];
    const int ln = t&63;
    for (int i=0;i<16;++i){
      int r = wv*16 + i;
      float2 v = *(const float2*)(xg + base + (size_t)r*DIM + 2*ln);
      float m  = wred64(v.x+v.y)*(1.f/128.f);
      float d0=v.x-m, d1=v.y-m;
      float var = wred64(d0*d0+d1*d1)*(1.f/128.f);
      float rs = rsqrtf(var + 1e-6f);
      float vz = var*rs*rs;
      float tt2 = s1p*rsqrtf(fmaf(s1p*s1p, vz, 1e-6f));
      float sc = rs*tt2;
      u32 pk = (u32)f2us(d0*sc) | ((u32)f2us(d1*sc)<<16);
      *(u32*)&A_l[r*136 + 2*ln] = pk;
    }
  }

  // ---- mm B: u = lnh @ w_in ----
  f32x4 uacc[8];
  #pragma unroll
  for (int n=0;n<8;++n) uacc[n]=(f32x4){0.f,0.f,0.f,0.f};
  for (int c=0;c<2;++c){
    __syncthreads();
    for (int i=t;i<1024;i+=256){
      int n=i>>3, cc=(i&7)*8;
      *(uint4*)&wT[n*72+cc] = *(const uint4*)&wint[(size_t)n*128 + c*64 + cc];
    }
    __syncthreads();
    #pragma unroll
    for (int k2=0;k2<2;++k2){
      bf16x8 av = *(const bf16x8*)&A_l[(m0+col)*136 + c*64 + k2*32 + quad*8];
      #pragma unroll
      for (int n=0;n<8;++n){
        bf16x8 bv = *(const bf16x8*)&wT[(n*16+col)*72 + k2*32 + quad*8];
        uacc[n] = __builtin_amdgcn_mfma_f32_16x16x32_bf16(av, bv, uacc[n], 0,0,0);
      }
    }
  }
  float u_c[8][4];
  #pragma unroll
  for (int n=0;n<8;++n){
    int nc = n*16 + col;
    float bi = b_in[nc];
    #pragma unroll
    for (int r=0;r<4;++r){
      int row = m0 + quad*4 + r;
      u_c[n][r] = uacc[n][r] + bi + pos[(size_t)(ck*CLEN+row)*DIM + nc];
    }
  }
  __syncthreads();     // all MFMAs done reading lnh (A_l) and wT

  // write u (bf16) into A_l (own wave's 16-row stripe)
  #pragma unroll
  for (int n=0;n<8;++n){
    #pragma unroll
    for (int r=0;r<4;++r)
      A_l[(m0+quad*4+r)*136 + n*16+col] = f2us(u_c[n][r]);
  }

  // ---- mm C: gi = sigmoid(u @ w_i + b_i) ----
  f32x4 gacc[8];
  #pragma unroll
  for (int n=0;n<8;++n) gacc[n]=(f32x4){0.f,0.f,0.f,0.f};
  for (int c=0;c<2;++c){
    __syncthreads();
    for (int i=t;i<1024;i+=256){
      int n=i>>3, cc=(i&7)*8;
      *(uint4*)&wT[n*72+cc] = *(const uint4*)&wit[(size_t)n*128 + c*64 + cc];
    }
    __syncthreads();
    #pragma unroll
    for (int k2=0;k2<2;++k2){
      bf16x8 av = *(const bf16x8*)&A_l[(m0+col)*136 + c*64 + k2*32 + quad*8];
      #pragma unroll
      for (int n=0;n<8;++n){
        bf16x8 bv = *(const bf16x8*)&wT[(n*16+col)*72 + k2*32 + quad*8];
        gacc[n] = __builtin_amdgcn_mfma_f32_16x16x32_bf16(av, bv, gacc[n], 0,0,0);
      }
    }
  }
  float gi_c[8][4];
  #pragma unroll
  for (int n=0;n<8;++n){
    float bi = b_i[n*16+col];
    #pragma unroll
    for (int r=0;r<4;++r) gi_c[n][r] = sigmoidf_(gacc[n][r]+bi);
  }

  // ---- mm D: gr ----
  f32x4 racc[8];
  #pragma unroll
  for (int n=0;n<8;++n) racc[n]=(f32x4){0.f,0.f,0.f,0.f};
  for (int c=0;c<2;++c){
    __syncthreads();
    for (int i=t;i<1024;i+=256){
      int n=i>>3, cc=(i&7)*8;
      *(uint4*)&wT[n*72+cc] = *(const uint4*)&wrt[(size_t)n*128 + c*64 + cc];
    }
    __syncthreads();
    #pragma unroll
    for (int k2=0;k2<2;++k2){
      bf16x8 av = *(const bf16x8*)&A_l[(m0+col)*136 + c*64 + k2*32 + quad*8];
      #pragma unroll
      for (int n=0;n<8;++n){
        bf16x8 bv = *(const bf16x8*)&wT[(n*16+col)*72 + k2*32 + quad*8];
        racc[n] = __builtin_amdgcn_mfma_f32_16x16x32_bf16(av, bv, racc[n], 0,0,0);
      }
    }
  }

  // a_t, b_t -> packed LDS + global (bf16)
  #pragma unroll
  for (int n=0;n<8;++n){
    int nc = n*16 + col;
    float la = __logf(avec[nc]);
    float br = b_r[nc];
    #pragma unroll
    for (int r=0;r<4;++r){
      int row = m0 + quad*4 + r;
      float g = sigmoidf_(racc[n][r]+br);
      float a = __expf(8.f*g*la);
      float bb = sqrtf(fmaxf(1.f-a*a,0.f))*gi_c[n][r]*u_c[n][r];
      u16 ab_ = f2us(a), bb_ = f2us(bb);
      abp[row*DIM+nc] = (u32)ab_ | ((u32)bb_<<16);
      atg[base + (size_t)row*DIM + nc] = ab_;
      btg[base + (size_t)row*DIM + nc] = bb_;
    }
  }
  __syncthreads();

  // chunk-local scans (over bf16 a,b -> consistent with k_scan) -> summaries
  const int sbase = (b*NCH+ck)*DIM;
  if (t < 128){
    float h=0.f, p=1.f;
    #pragma unroll 4
    for (int tt=0;tt<CLEN;++tt){
      u32 v=abp[tt*DIM+t];
      float a=us2f((u16)v), bb=us2f((u16)(v>>16));
      h=fmaf(a,h,bb); p*=a;
    }
    Ag[sbase+t]=p; Bfg[sbase+t]=h;
  } else {
    int ch=t-128; float h=0.f;
    #pragma unroll 4
    for (int tt=CLEN-1;tt>=0;--tt){
      u32 v=abp[tt*DIM+ch];
      h=fmaf(us2f((u16)v),h,us2f((u16)(v>>16)));
    }
    Bbg[sbase+ch]=h;
  }
}

// ------------------------------------------------ K2: prefix over chunk summaries
__global__ __launch_bounds__(128) void k_chunkscan(
    const float* __restrict__ Ag, const float* __restrict__ Bfg, const float* __restrict__ Bbg,
    float* __restrict__ Hf, float* __restrict__ Hb)
{
  const int dir = blockIdx.x >> 3, b = blockIdx.x & 7, ch = threadIdx.x;
  float s = 0.f;
  if (dir==0){
    for (int c=0;c<NCH;++c){ size_t i=((size_t)(b*NCH+c))*DIM+ch; Hf[i]=s; s=fmaf(Ag[i],s,Bfg[i]); }
  } else {
    for (int c=NCH-1;c>=0;--c){ size_t i=((size_t)(b*NCH+c))*DIM+ch; Hb[i]=s; s=fmaf(Ag[i],s,Bbg[i]); }
  }
}

// -------------------- K3: load a,b + seeded scan + MFMA out-proj + residual (65 KB LDS)
__global__ __launch_bounds__(256,2) void k_scan(
    const u16* __restrict__ atg, const u16* __restrict__ btg,
    const float* __restrict__ Hf, const float* __restrict__ Hb,
    const float* __restrict__ xg, const u16* __restrict__ wot, const float* __restrict__ b_out,
    const float* __restrict__ aff, float* __restrict__ outg)
{
  __shared__ u16 sm[CLEN*DIM*2];    // 32 KB: a_l | b_l ; reused as wol [128][72]
  __shared__ u16 hcat[CLEN*264];    // 33 KB
  u16* a_l = sm;
  u16* b_l = sm + CLEN*DIM;
  const int t  = threadIdx.x;
  const int b  = blockIdx.x >> 7;
  const int ck = blockIdx.x & (NCH-1);
  const size_t base = ((size_t)(b*SEQ + ck*CLEN))*DIM;

  {
    const uint4* sa=(const uint4*)(atg+base); const uint4* sb=(const uint4*)(btg+base);
    for (int i=t;i<1024;i+=256){ ((uint4*)a_l)[i]=sa[i]; ((uint4*)b_l)[i]=sb[i]; }
  }
  __syncthreads();

  // seeded scans -> hcat
  const int pbase=(b*NCH+ck)*DIM;
  if (t<128){
    float h=Hf[pbase+t];
    #pragma unroll 4
    for (int tt=0;tt<CLEN;++tt){
      h=fmaf(us2f(a_l[tt*DIM+t]),h,us2f(b_l[tt*DIM+t]));
      hcat[tt*264+t]=f2us(h);
    }
  } else {
    int ch=t-128;
    float h=Hb[pbase+ch];
    #pragma unroll 4
    for (int tt=CLEN-1;tt>=0;--tt){
      h=fmaf(us2f(a_l[tt*DIM+ch]),h,us2f(b_l[tt*DIM+ch]));
      hcat[tt*264+128+ch]=f2us(h);
    }
  }
  __syncthreads();

  // MFMA out-proj: C[64][128] = hcat[64][256] @ w_out[256][128]
  const int lane=t&63, wv=t>>6, col=lane&15, quad=lane>>4;
  const int m0 = wv*16;
  u16* wol = sm;                      // [128][72], overlaps a_l/b_l (free now)
  f32x4 acc[8];
  #pragma unroll
  for (int n=0;n<8;++n) acc[n]=(f32x4){0.f,0.f,0.f,0.f};
  for (int chk=0; chk<4; ++chk){      // K-chunks of 64
    for (int i=t;i<1024;i+=256){
      int n=i>>3, c=(i&7)*8;
      *(uint4*)&wol[n*72 + c] = *(const uint4*)&wot[(size_t)n*256 + chk*64 + c];
    }
    __syncthreads();
    #pragma unroll
    for (int k2=0;k2<2;++k2){
      bf16x8 av = *(const bf16x8*)&hcat[(m0+col)*264 + chk*64 + k2*32 + quad*8];
      #pragma unroll
      for (int n=0;n<8;++n){
        bf16x8 bv = *(const bf16x8*)&wol[(n*16+col)*72 + k2*32 + quad*8];
        acc[n] = __builtin_amdgcn_mfma_f32_16x16x32_bf16(av, bv, acc[n], 0,0,0);
      }
    }
    __syncthreads();
  }
  const float g1=aff[b*6+2];
  #pragma unroll
  for (int n=0;n<8;++n){
    int nc = n*16 + col;
    float bo = b_out[nc];
    #pragma unroll
    for (int r=0;r<4;++r){
      int row = m0 + quad*4 + r;
      size_t gi = base + (size_t)row*DIM + nc;
      outg[gi] = fmaf(g1, acc[n][r]+bo, xg[gi]);
    }
  }
}

// -------------------- K4: cLN2 + fused MFMA gelu MLP + gated residual (53 KB LDS)
__global__ __launch_bounds__(256,3) void k_mlp(
    const u16* __restrict__ w1t, const float* __restrict__ b1v,
    const u16* __restrict__ w2t, const float* __restrict__ b2v,
    const float* __restrict__ aff, float* __restrict__ outg)
{
  __shared__ u16 h2l[CLEN*136];   // 17408 B: h2 (A-operand)
  __shared__ u16 wbuf[128*72];    // 18432 B: 64-K chunk of w1 or w2 panel
  __shared__ u16 m1p[CLEN*136];   // 17408 B: gelu panel (A-operand for mm2)
  const int t=threadIdx.x;
  const int b=blockIdx.x>>7;
  const size_t base=(size_t)blockIdx.x*CLEN*DIM;
  const int lane=t&63, wv=t>>6, col=lane&15, quad=lane>>4;
  const int m0 = wv*16;
  const float s2p=1.f+aff[b*6+3], b2a=aff[b*6+4], g2=aff[b*6+5];

  // step 0: h2 = (1+s2)*LN(x1)+b2 -> h2l (bf16)
  {
    const int cg=t&15, rg=t>>4, j0=cg*8, r0=rg*4;
    #pragma unroll
    for (int ii=0;ii<4;++ii){
      int r=r0+ii;
      const float* xo = outg + base + (size_t)r*DIM + j0;
      float4 a = *(const float4*)xo;
      float4 bq = *(const float4*)(xo+4);
      float o[8]={a.x,a.y,a.z,a.w,bq.x,bq.y,bq.z,bq.w};
      float s=0.f;
      #pragma unroll
      for (int j=0;j<8;++j) s+=o[j];
      s=red16(s); float m=s*(1.f/128.f);
      float q2=0.f;
      #pragma unroll
      for (int j=0;j<8;++j){ float d=o[j]-m; q2+=d*d; }
      q2=red16(q2); float rs=rsqrtf(q2*(1.f/128.f)+1e-6f);
      u32 pk[4];
      #pragma unroll
      for (int q=0;q<4;++q){
        float a0=fmaf((o[2*q]-m)*rs,   s2p, b2a);
        float a1=fmaf((o[2*q+1]-m)*rs, s2p, b2a);
        pk[q]= (u32)f2us(a0) | ((u32)f2us(a1)<<16);
      }
      *(uint4*)&h2l[r*136+j0] = make_uint4(pk[0],pk[1],pk[2],pk[3]);
    }
  }

  f32x4 acc2[8];
  #pragma unroll
  for (int n=0;n<8;++n) acc2[n]=(f32x4){0.f,0.f,0.f,0.f};

  for (int p=0;p<4;++p){              // panels: 128 cols of m1 == 128 K-rows of mm2
    // ---- mm1 panel: C1p[64][128] = h2[64][128] @ w1[:,p*128:(p+1)*128] ----
    f32x4 accp[8];
    #pragma unroll
    for (int n=0;n<8;++n) accp[n]=(f32x4){0.f,0.f,0.f,0.f};
    for (int c=0;c<2;++c){
      __syncthreads();
      for (int i=t;i<1024;i+=256){
        int n=i>>3, cc=(i&7)*8;
        *(uint4*)&wbuf[n*72+cc] = *(const uint4*)&w1t[(size_t)(p*128+n)*128 + c*64 + cc];
      }
      __syncthreads();
      #pragma unroll
      for (int k2=0;k2<2;++k2){
        bf16x8 av = *(const bf16x8*)&h2l[(m0+col)*136 + c*64 + k2*32 + quad*8];
        #pragma unroll
        for (int n=0;n<8;++n){
          bf16x8 bv = *(const bf16x8*)&wbuf[(n*16+col)*72 + k2*32 + quad*8];
          accp[n] = __builtin_amdgcn_mfma_f32_16x16x32_bf16(av, bv, accp[n], 0,0,0);
        }
      }
    }
    // gelu -> m1p (C-layout rows == own wave's 16-row stripe; A-read also own stripe)
    #pragma unroll
    for (int n=0;n<8;++n){
      int nc = n*16 + col;
      float bb = b1v[p*128 + nc];
      #pragma unroll
      for (int r=0;r<4;++r)
        m1p[(m0+quad*4+r)*136 + nc] = f2us(gelu_tanh(accp[n][r] + bb));
    }
    // ---- mm2 partial: acc2 += m1p[64][128] @ w2[p*128:(p+1)*128, :] ----
    for (int c=0;c<2;++c){
      __syncthreads();
      for (int i=t;i<1024;i+=256){
        int n=i>>3, cc=(i&7)*8;
        *(uint4*)&wbuf[n*72+cc] = *(const uint4*)&w2t[(size_t)n*512 + p*128 + c*64 + cc];
      }
      __syncthreads();
      #pragma unroll
      for (int k2=0;k2<2;++k2){
        bf16x8 av = *(const bf16x8*)&m1p[(m0+col)*136 + c*64 + k2*32 + quad*8];
        #pragma unroll
        for (int n=0;n<8;++n){
          bf16x8 bv = *(const bf16x8*)&wbuf[(n*16+col)*72 + k2*32 + quad*8];
          acc2[n] = __builtin_amdgcn_mfma_f32_16x16x32_bf16(av, bv, acc2[n], 0,0,0);
        }
      }
    }
  }
  // epilogue: out = x1 + g2*(C2 + b2)
  #pragma unroll
  for (int n=0;n<8;++n){
    int nc = n*16 + col;
    float bb = b2v[nc];
    #pragma unroll
    for (int r=0;r<4;++r){
      int row = m0 + quad*4 + r;
      size_t gi = base + (size_t)row*DIM + nc;
      outg[gi] = fmaf(g2, acc2[n][r] + bb, outg[gi]);
    }
  }
}

// ----------------------------------------------------------------------------
extern "C" void kernel_launch(void* const* d_in, const int* in_sizes, int n_in,
                              void* d_out, int out_size, void* d_ws, size_t ws_size,
                              hipStream_t stream)
{
  (void)in_sizes; (void)n_in; (void)out_size; (void)ws_size;
  const float* x   =(const float*)d_in[0];
  const float* c   =(const float*)d_in[1];
  const float* c1sw=(const float*)d_in[2];  const float* c1sb=(const float*)d_in[3];
  const float* c1bw=(const float*)d_in[4];  const float* c1bb=(const float*)d_in[5];
  const float* g1w =(const float*)d_in[6];  const float* g1b =(const float*)d_in[7];
  const float* win =(const float*)d_in[8];  const float* binv=(const float*)d_in[9];
  const float* pos =(const float*)d_in[10];
  const float* wi  =(const float*)d_in[11]; const float* biv =(const float*)d_in[12];
  const float* wr  =(const float*)d_in[13]; const float* brv =(const float*)d_in[14];
  const float* av  =(const float*)d_in[15];
  const float* wout=(const float*)d_in[16]; const float* bout=(const float*)d_in[17];
  const float* c2sw=(const float*)d_in[18]; const float* c2sb=(const float*)d_in[19];
  const float* c2bw=(const float*)d_in[20]; const float* c2bb=(const float*)d_in[21];
  const float* g2w =(const float*)d_in[22]; const float* g2b =(const float*)d_in[23];
  const float* w1  =(const float*)d_in[24]; const float* b1v =(const float*)d_in[25];
  const float* w2  =(const float*)d_in[26]; const float* b2v =(const float*)d_in[27];

  // workspace layout (~36.6 MB total)
  float* wsf  = (float*)d_ws;
  float* Ag   = wsf;
  float* Bfg  = Ag   + 131072;
  float* Bbg  = Bfg  + 131072;
  float* Hf   = Bbg  + 131072;
  float* Hb   = Hf   + 131072;
  float* aff  = Hb   + 131072;       // 48 (pad 64)
  u16*   w1t  = (u16*)(aff + 64);    // [512][128]
  u16*   w2t  = w1t + 65536;         // [128][512]
  u16*   wot  = w2t + 65536;         // [128][256]
  u16*   wint = wot + 32768;         // [128][128]
  u16*   wit  = wint + 16384;
  u16*   wrt  = wit  + 16384;
  u16*   atg  = wrt  + 16384;        // [BSZ*SEQ*DIM] bf16
  u16*   btg  = atg  + 8388608;

  float* outg = (float*)d_out;

  k_aff<<<dim3(1),dim3(64),0,stream>>>(c, c1sw,c1bw,g1w,c2sw,c2bw,g2w,
                                       c1sb,c1bb,g1b,c2sb,c2bb,g2b, aff);
  k_prep<<<dim3(256),dim3(256),0,stream>>>(w1,w2,wout,win,wi,wr,
                                           w1t,w2t,wot,wint,wit,wrt);
  k_pre<<<dim3(BSZ*NCH),dim3(256),0,stream>>>(x,wint,binv,pos,wit,biv,wrt,brv,av,aff,
                                              atg,btg, Ag,Bfg,Bbg);
  k_chunkscan<<<dim3(16),dim3(128),0,stream>>>(Ag,Bfg,Bbg,Hf,Hb);
  k_scan<<<dim3(BSZ*NCH),dim3(256),0,stream>>>(atg,btg,Hf,Hb,x,wot,bout,aff,outg);
  k_mlp<<<dim3(BSZ*NCH),dim3(256),0,stream>>>(w1t,b1v,w2t,b2v,aff,outg);
}